// Round 5
// baseline (521.329 us; speedup 1.0000x reference)
//
#include <hip/hip_runtime.h>
#include <math.h>

static constexpr int Cdim = 32;   // C
static constexpr int NBES = 8;    // NB
static constexpr int HDIM = 64;   // H
static constexpr int ZDIM = 10;   // Z

typedef _Float16 half8 __attribute__((ext_vector_type(8)));
typedef _Float16 half4 __attribute__((ext_vector_type(4)));
typedef float floatx4 __attribute__((ext_vector_type(4)));

__device__ __forceinline__ float silu_f(float x) {
    return x / (1.0f + __expf(-x));
}

// ---------------- node init ----------------
__global__ __launch_bounds__(256)
void k_node_init(const float* __restrict__ attrs, const float* __restrict__ W_embed,
                 const float* __restrict__ atomE, int* __restrict__ elem,
                 float* hOut /* feats base, stride 576 */, float* __restrict__ energy,
                 int* __restrict__ deg, int* __restrict__ gcnt, int N)
{
    int n = blockIdx.x * blockDim.x + threadIdx.x;
    if (n == 0) *gcnt = 0;
    if (n >= N) return;
    int e = 0; float best = -1.0f;
    #pragma unroll
    for (int z = 0; z < ZDIM; ++z) {
        float v = attrs[n * ZDIM + z];
        if (v > best) { best = v; e = z; }
    }
    elem[n] = e;
    #pragma unroll
    for (int c = 0; c < Cdim; ++c) hOut[(size_t)n * 576 + c] = W_embed[e * Cdim + c];
    energy[n] = atomE[e];
    deg[n] = 0;
}

// ---------------- ZBL + degree count + wave-aggregated active-pair compaction ----------------
__global__ __launch_bounds__(256)
void k_edge_zbl(const float* __restrict__ pos, const int* __restrict__ snd,
                const int* __restrict__ rcv, const int* __restrict__ elem,
                float* __restrict__ energy, int* __restrict__ deg,
                int2* __restrict__ pairs, int* __restrict__ gcnt, int E)
{
    int e = blockIdx.x * blockDim.x + threadIdx.x;
    if (e >= E) return;
    int s = snd[e], t = rcv[e];
    float dx = pos[3*t+0] - pos[3*s+0];
    float dy = pos[3*t+1] - pos[3*s+1];
    float dz = pos[3*t+2] - pos[3*s+2];
    float r  = sqrtf(dx*dx + dy*dy + dz*dz + 1e-12f);
    float u  = r / 5.0f;
    if (!(u < 1.0f)) return;
    // compaction (all surviving lanes)
    unsigned long long mask = __ballot(1);
    int lane = threadIdx.x & 63;
    int leader = __ffsll((long long)mask) - 1;
    int prefix = __popcll(mask & ((1ull << lane) - 1ull));
    int base = 0;
    if (lane == leader) base = atomicAdd(gcnt, __popcll(mask));
    base = __shfl(base, leader);
    pairs[base + prefix] = make_int2(s, t);

    float u2 = u*u, u5 = u2*u2*u;
    float fcut = 1.0f - 21.0f*u5 + 35.0f*u5*u - 15.0f*u5*u2;
    float zi = (float)(elem[s] + 1);
    float zj = (float)(elem[t] + 1);
    float a  = 0.4685f / (powf(zi, 0.23f) + powf(zj, 0.23f));
    float xx = r / a;
    float phi = 0.1818f*expf(-3.2f*xx) + 0.5099f*expf(-0.9423f*xx)
              + 0.2802f*expf(-0.4029f*xx) + 0.02817f*expf(-0.2016f*xx);
    float v = 14.3996f * zi * zj / r * phi * fcut;
    atomicAdd(&energy[t], 0.5f * v);
    atomicAdd(&deg[t], 1);
}

// ---------------- single-block exclusive scan ----------------
__global__ __launch_bounds__(1024)
void k_scan(const int* __restrict__ deg, int* __restrict__ rowptr,
            int* __restrict__ cursor, int N)
{
    __shared__ int wsum[16];
    __shared__ int chunk_base;
    int tid = threadIdx.x;
    int lane = tid & 63, w = tid >> 6;
    if (tid == 0) chunk_base = 0;
    __syncthreads();
    for (int base = 0; base < N; base += 1024) {
        int i = base + tid;
        int v = (i < N) ? deg[i] : 0;
        int s = v;
        #pragma unroll
        for (int d = 1; d < 64; d <<= 1) {
            int u = __shfl_up(s, d);
            if (lane >= d) s += u;
        }
        if (lane == 63) wsum[w] = s;
        __syncthreads();
        if (w == 0 && lane < 16) {
            int x = wsum[lane];
            #pragma unroll
            for (int d = 1; d < 16; d <<= 1) {
                int u = __shfl_up(x, d);
                if (lane >= d) x += u;
            }
            wsum[lane] = x;
        }
        __syncthreads();
        int wave_off = (w == 0) ? 0 : wsum[w - 1];
        int excl = chunk_base + wave_off + (s - v);
        if (i < N) { rowptr[i] = excl; cursor[i] = excl; }
        int total = wsum[15];
        __syncthreads();
        if (tid == 0) chunk_base += total;
        __syncthreads();
    }
    if (tid == 0) rowptr[N] = chunk_base;
}

// ---------------- place compacted pairs into CSR slots ----------------
__global__ __launch_bounds__(256)
void k_place(const int2* __restrict__ pairs, const int* __restrict__ gcnt,
             int* __restrict__ cursor, int* __restrict__ eS, int* __restrict__ eT)
{
    int i = blockIdx.x * blockDim.x + threadIdx.x;
    if (i >= *gcnt) return;
    int2 p = pairs[i];
    int slot = atomicAdd(&cursor[p.y], 1);
    eS[slot] = p.x;
    eT[slot] = p.y;
}

// ---------------- h1 = h @ Wlin[i] ----------------
__global__ __launch_bounds__(256)
void k_h1(const float* h, const float* __restrict__ Wlin,
          float* __restrict__ h1, int N)
{
    __shared__ float sW[Cdim * Cdim];
    for (int t = threadIdx.x; t < Cdim * Cdim; t += 256) sW[t] = Wlin[t];
    __syncthreads();
    int n = blockIdx.x * blockDim.x + threadIdx.x;
    if (n >= N) return;
    float hv[Cdim];
    #pragma unroll
    for (int c4 = 0; c4 < 8; ++c4) {
        float4 v = *(const float4*)(h + (size_t)n * 576 + c4 * 4);
        hv[c4*4+0] = v.x; hv[c4*4+1] = v.y; hv[c4*4+2] = v.z; hv[c4*4+3] = v.w;
    }
    float acc[Cdim];
    #pragma unroll
    for (int d = 0; d < Cdim; ++d) acc[d] = 0.f;
    #pragma unroll
    for (int c = 0; c < Cdim; ++c) {
        float hc = hv[c];
        #pragma unroll
        for (int d = 0; d < Cdim; ++d) acc[d] += hc * sW[c * Cdim + d];
    }
    #pragma unroll
    for (int d4 = 0; d4 < 8; ++d4)
        *(float4*)(h1 + (size_t)n * Cdim + d4 * 4) =
            make_float4(acc[d4*4], acc[d4*4+1], acc[d4*4+2], acc[d4*4+3]);
}

// ---------------- radial MLP via f16 MFMA (swapped operands -> packed stores) ----------------
__global__ __launch_bounds__(256, 2)
void k_mlp(const int* __restrict__ eS, const int* __restrict__ eT,
           const float* __restrict__ pos,
           const float* __restrict__ W0, const float* __restrict__ W1,
           const float* __restrict__ W2, const float* __restrict__ W3,
           const int* __restrict__ eactp, _Float16* __restrict__ w_out)
{
    __shared__ __align__(16) _Float16 sWt0[64*32];   // W0^T rows=out-ch, 64B rows, swz (n&3)<<4
    __shared__ __align__(16) _Float16 sWt1[64*64];   // 128B rows, swz (n&7)<<4
    __shared__ __align__(16) _Float16 sWt2[64*64];
    __shared__ __align__(16) _Float16 sWt3[96*64];
    __shared__ __align__(16) _Float16 sAct[4][64*64];

    for (int idx = threadIdx.x; idx < 64*32; idx += 256) {
        int n = idx >> 5, k = idx & 31;
        float v = (k < NBES) ? W0[k*64 + n] : 0.f;
        *(_Float16*)((char*)sWt0 + n*64 + ((k*2) ^ ((n&3)<<4))) = (_Float16)v;
    }
    for (int idx = threadIdx.x; idx < 64*64; idx += 256) {
        int k = idx >> 6, n = idx & 63;
        int byo = n*128 + ((k*2) ^ ((n&7)<<4));
        *(_Float16*)((char*)sWt1 + byo) = (_Float16)W1[idx];
        *(_Float16*)((char*)sWt2 + byo) = (_Float16)W2[idx];
    }
    for (int idx = threadIdx.x; idx < 64*96; idx += 256) {
        int k = idx / 96, n = idx - k*96;
        *(_Float16*)((char*)sWt3 + n*128 + ((k*2) ^ ((n&7)<<4))) = (_Float16)W3[idx];
    }
    __syncthreads();

    const int wid = threadIdx.x >> 6, lane = threadIdx.x & 63;
    const int l15 = lane & 15, lh = lane >> 4;
    const int Eact = *eactp;
    char* actc = (char*)sAct[wid];

    // hoisted weight fragments (A-operand side: row = out-channel = l15-based)
    half8 w1f[4], w2f[4][2], w3f[4][2], w4f[6][2];
    #pragma unroll
    for (int nt = 0; nt < 4; ++nt) {
        int nn = nt*16 + l15;
        w1f[nt] = *(half8*)((char*)sWt0 + nn*64 + ((lh*16) ^ ((nn&3)<<4)));
        #pragma unroll
        for (int ks = 0; ks < 2; ++ks) {
            w2f[nt][ks] = *(half8*)((char*)sWt1 + nn*128 + ((ks*64 + lh*16) ^ ((nn&7)<<4)));
            w3f[nt][ks] = *(half8*)((char*)sWt2 + nn*128 + ((ks*64 + lh*16) ^ ((nn&7)<<4)));
        }
    }
    #pragma unroll
    for (int nt = 0; nt < 6; ++nt) {
        int nn = nt*16 + l15;
        #pragma unroll
        for (int ks = 0; ks < 2; ++ks)
            w4f[nt][ks] = *(half8*)((char*)sWt3 + nn*128 + ((ks*64 + lh*16) ^ ((nn&7)<<4)));
    }

    for (int c0 = (blockIdx.x*4 + wid)*64; c0 < Eact; c0 += gridDim.x*256) {
        int k = c0 + lane;
        bool okl = k < Eact;
        int kk = okl ? k : 0;
        int s = eS[kk], t = eT[kk];
        float dx = pos[3*t+0]-pos[3*s+0];
        float dy = pos[3*t+1]-pos[3*s+1];
        float dz = pos[3*t+2]-pos[3*s+2];
        float r  = sqrtf(dx*dx + dy*dy + dz*dz + 1e-12f);
        float inv_r = 1.0f / r;
        float u  = r / 5.0f;
        float u2 = u*u, u5 = u2*u2*u;
        float fcut = 1.0f - 21.0f*u5 + 35.0f*u5*u - 15.0f*u5*u2;
        float coef = 0.632455532f * inv_r * fcut;
        if (!okl) coef = 0.f;
        half8 rv;
        #pragma unroll
        for (int j = 0; j < NBES; ++j)
            rv[j] = (_Float16)(coef * __sinf((float)(j+1) * 0.628318531f * r));
        {
            int sw = (lane & 7) << 4;
            half8 zz = {};
            *(half8*)(actc + lane*128 + ( 0 ^ sw)) = rv;
            *(half8*)(actc + lane*128 + (16 ^ sw)) = zz;
            *(half8*)(actc + lane*128 + (32 ^ sw)) = zz;
            *(half8*)(actc + lane*128 + (48 ^ sw)) = zz;
        }
        __builtin_amdgcn_sched_barrier(0);

        // ---- L1: K=32; D = W1^T·Act^T -> lane holds 4 contiguous channels of edge l15 ----
        #pragma unroll
        for (int mt = 0; mt < 4; ++mt) {
            int rr = mt*16 + l15;
            int swz = (rr & 7) << 4;
            half8 act = *(half8*)(actc + rr*128 + ((lh*16) ^ swz));
            #pragma unroll
            for (int nt = 0; nt < 4; ++nt) {
                floatx4 z = {0.f,0.f,0.f,0.f};
                floatx4 d = __builtin_amdgcn_mfma_f32_16x16x32_f16(w1f[nt], act, z, 0,0,0);
                half4 pk;
                #pragma unroll
                for (int j = 0; j < 4; ++j) pk[j] = (_Float16)silu_f(d[j]);
                *(half4*)(actc + rr*128 + ((nt*32 + lh*8) ^ swz)) = pk;
            }
        }
        __builtin_amdgcn_sched_barrier(0);

        // ---- L2, L3: K=64 ----
        #pragma unroll
        for (int layer = 0; layer < 2; ++layer) {
            #pragma unroll
            for (int mt = 0; mt < 4; ++mt) {
                int rr = mt*16 + l15;
                int swz = (rr & 7) << 4;
                half8 a0 = *(half8*)(actc + rr*128 + ((      lh*16) ^ swz));
                half8 a1 = *(half8*)(actc + rr*128 + ((64 + lh*16) ^ swz));
                #pragma unroll
                for (int nt = 0; nt < 4; ++nt) {
                    floatx4 z = {0.f,0.f,0.f,0.f};
                    if (layer == 0) {
                        z = __builtin_amdgcn_mfma_f32_16x16x32_f16(w2f[nt][0], a0, z, 0,0,0);
                        z = __builtin_amdgcn_mfma_f32_16x16x32_f16(w2f[nt][1], a1, z, 0,0,0);
                    } else {
                        z = __builtin_amdgcn_mfma_f32_16x16x32_f16(w3f[nt][0], a0, z, 0,0,0);
                        z = __builtin_amdgcn_mfma_f32_16x16x32_f16(w3f[nt][1], a1, z, 0,0,0);
                    }
                    half4 pk;
                    #pragma unroll
                    for (int j = 0; j < 4; ++j) pk[j] = (_Float16)silu_f(z[j]);
                    *(half4*)(actc + rr*128 + ((nt*32 + lh*8) ^ swz)) = pk;
                }
            }
            __builtin_amdgcn_sched_barrier(0);
        }

        // ---- L4: 96 out channels -> packed global stores ----
        #pragma unroll
        for (int mt = 0; mt < 4; ++mt) {
            int rr = mt*16 + l15;
            int swz = (rr & 7) << 4;
            half8 a0 = *(half8*)(actc + rr*128 + ((      lh*16) ^ swz));
            half8 a1 = *(half8*)(actc + rr*128 + ((64 + lh*16) ^ swz));
            int e = c0 + rr;
            bool oke = e < Eact;
            #pragma unroll
            for (int nt = 0; nt < 6; ++nt) {
                floatx4 z = {0.f,0.f,0.f,0.f};
                z = __builtin_amdgcn_mfma_f32_16x16x32_f16(w4f[nt][0], a0, z, 0,0,0);
                z = __builtin_amdgcn_mfma_f32_16x16x32_f16(w4f[nt][1], a1, z, 0,0,0);
                half4 pk;
                #pragma unroll
                for (int j = 0; j < 4; ++j) pk[j] = (_Float16)z[j];
                if (oke)
                    *(half4*)(w_out + (size_t)e*96 + nt*16 + lh*4) = pk;
            }
        }
        __builtin_amdgcn_sched_barrier(0);
    }
}

// ---------------- gather: 8 lanes per node, register segmented reduction ----------------
__global__ __launch_bounds__(256)
void k_gather(const int* __restrict__ rowptr, const int* __restrict__ eS,
              const float* __restrict__ pos,
              const float* __restrict__ h1, const _Float16* __restrict__ w_out,
              float* __restrict__ feats, int N)
{
    int g = threadIdx.x >> 3;
    int j = threadIdx.x & 7;
    int n = blockIdx.x * 32 + g;
    if (n >= N) return;
    int c0 = j * 4;

    float acc[9][4];
    #pragma unroll
    for (int m = 0; m < 9; ++m)
        #pragma unroll
        for (int q = 0; q < 4; ++q) acc[m][q] = 0.f;

    float px = pos[3*n+0], py = pos[3*n+1], pz = pos[3*n+2];
    int lo = rowptr[n], hi = rowptr[n+1];

    for (int k = lo; k < hi; ++k) {
        int s = eS[k];
        float dx = px - pos[3*s+0];
        float dy = py - pos[3*s+1];
        float dz = pz - pos[3*s+2];
        float r  = sqrtf(dx*dx + dy*dy + dz*dz + 1e-12f);
        float inv_r = 1.0f / r;
        float ux = dx*inv_r, uy = dy*inv_r, uz = dz*inv_r;
        const float s3 = 1.73205081f, s5 = 2.23606798f, s15 = 3.87298335f;
        float sh[9];
        sh[0] = 1.0f;
        sh[1] = s3 * ux; sh[2] = s3 * uy; sh[3] = s3 * uz;
        sh[4] = s15 * ux * uy; sh[5] = s15 * uy * uz;
        sh[6] = 0.5f * s5 * (3.0f * uz * uz - 1.0f);
        sh[7] = s15 * ux * uz;
        sh[8] = 0.5f * s15 * (ux * ux - uy * uy);

        const _Float16* wp = w_out + (size_t)k * 96 + c0;
        half4 w0v = *(const half4*)(wp);
        half4 w1v = *(const half4*)(wp + 32);
        half4 w2v = *(const half4*)(wp + 64);
        float4 hv = *(const float4*)(h1 + (size_t)s * Cdim + c0);
        float hb[4] = {hv.x, hv.y, hv.z, hv.w};

        #pragma unroll
        for (int q = 0; q < 4; ++q) {
            float m0 = hb[q] * (float)w0v[q];
            float m1 = hb[q] * (float)w1v[q];
            float m2 = hb[q] * (float)w2v[q];
            acc[0][q] += m0;
            acc[1][q] += sh[1] * m1;
            acc[2][q] += sh[2] * m1;
            acc[3][q] += sh[3] * m1;
            acc[4][q] += sh[4] * m2;
            acc[5][q] += sh[5] * m2;
            acc[6][q] += sh[6] * m2;
            acc[7][q] += sh[7] * m2;
            acc[8][q] += sh[8] * m2;
        }
    }

    float* Ar = feats + (size_t)n * 576 + 288 + c0;
    #pragma unroll
    for (int m = 0; m < 9; ++m)
        *(float4*)(Ar + m * Cdim) = make_float4(acc[m][0], acc[m][1], acc[m][2], acc[m][3]);
}

// ---------------- fused epilogue: out_m + scalar channel + energy, 8 lanes/node ----------------
template<int ITER>
__global__ __launch_bounds__(256)
void k_epilogue(float* AO, const int* __restrict__ elem,
                const float* __restrict__ Wprod, const float* __restrict__ Wsc,
                const float* __restrict__ Wp, const float* __restrict__ w_ro1,
                const float* __restrict__ W_m1, const float* __restrict__ w_m2,
                float* __restrict__ energy, int N)
{
    __shared__ float sWp[3 * 1024];
    __shared__ float sM1[512];
    __shared__ float sm2[16];
    __shared__ float sro[32];
    __shared__ float sNode[32][321];   // [A 0..287 | h 288..319], pad to 321

    for (int t = threadIdx.x; t < 3072; t += 256) sWp[t] = Wprod[t];
    for (int t = threadIdx.x; t < 512; t += 256) sM1[t] = W_m1[t];
    if (threadIdx.x < 16) sm2[threadIdx.x] = w_m2[threadIdx.x];
    if (threadIdx.x < 32) sro[threadIdx.x] = w_ro1[threadIdx.x];

    int nbase = blockIdx.x * 32;
    for (int t = threadIdx.x; t < 32 * 72; t += 256) {
        int g = t / 72, q = t - g * 72;
        int n = nbase + g;
        if (n < N)
            *(float4*)&sNode[g][q * 4] = *(const float4*)(AO + (size_t)n * 576 + 288 + q * 4);
    }
    for (int t = threadIdx.x; t < 32 * 8; t += 256) {
        int g = t / 8, q = t - g * 8;
        int n = nbase + g;
        if (n < N)
            *(float4*)&sNode[g][288 + q * 4] = *(const float4*)(AO + (size_t)n * 576 + q * 4);
    }
    __syncthreads();

    int g = threadIdx.x >> 3, j = threadIdx.x & 7, c0 = j * 4;
    int n = nbase + g;
    if (n >= N) return;
    int el = elem[n];
    const float* An = sNode[g];
    const int outslot = (ITER == 0) ? 0 : 288;

    // scalar channel hs[c0..c0+3]
    float hs[4] = {0.f, 0.f, 0.f, 0.f};
    #pragma unroll 8
    for (int c = 0; c < 32; ++c) {
        float av = An[c] * 0.0625f;
        #pragma unroll
        for (int d = 0; d < 4; ++d) hs[d] += av * sWp[c * 32 + c0 + d];
    }
    const float* Ws = Wsc + (size_t)el * 1024;
    #pragma unroll 8
    for (int c = 0; c < 32; ++c) {
        float hc = An[288 + c];
        float4 wv = *(const float4*)(Ws + c * 32 + c0);
        hs[0] += hc * wv.x; hs[1] += hc * wv.y; hs[2] += hc * wv.z; hs[3] += hc * wv.w;
    }
    const float* wpb = Wp + el * 32;
    #pragma unroll
    for (int d = 0; d < 4; ++d) {
        float A = An[c0 + d] * 0.0625f, A2 = A * A;
        hs[d] += wpb[c0 + d] * A + wpb[320 + c0 + d] * A2 + wpb[640 + c0 + d] * (A2 * A);
    }

    // energy readout (cross-lane reduce within the 8-lane group)
    float eadd;
    if (ITER == 0) {
        float acc = 0.f;
        #pragma unroll
        for (int d = 0; d < 4; ++d) acc += hs[d] * sro[c0 + d];
        acc += __shfl_xor(acc, 1); acc += __shfl_xor(acc, 2); acc += __shfl_xor(acc, 4);
        eadd = acc;
    } else {
        float tj[16];
        #pragma unroll
        for (int q = 0; q < 16; ++q) {
            float tv = 0.f;
            #pragma unroll
            for (int d = 0; d < 4; ++d) tv += hs[d] * sM1[(c0 + d) * 16 + q];
            tv += __shfl_xor(tv, 1); tv += __shfl_xor(tv, 2); tv += __shfl_xor(tv, 4);
            tj[q] = tv;
        }
        float acc = 0.f;
        #pragma unroll
        for (int q = 0; q < 16; ++q) acc += silu_f(tj[q]) * sm2[q];
        eadd = acc;
    }
    if (j == 0) energy[n] += eadd;

    // write scalar channel
    *(float4*)(AO + (size_t)n * 576 + outslot + c0) = make_float4(hs[0], hs[1], hs[2], hs[3]);

    // out[m] = (A[m]/16) @ Wprod[L[m]] for m=1..8
    #pragma unroll
    for (int m = 1; m <= 8; ++m) {
        const float* wb = sWp + ((m <= 3) ? 1 : 2) * 1024;
        const float* Am = An + m * 32;
        float o[4] = {0.f, 0.f, 0.f, 0.f};
        #pragma unroll 8
        for (int c = 0; c < 32; ++c) {
            float av = Am[c] * 0.0625f;
            #pragma unroll
            for (int d = 0; d < 4; ++d) o[d] += av * wb[c * 32 + c0 + d];
        }
        *(float4*)(AO + (size_t)n * 576 + outslot + m * 32 + c0) = make_float4(o[0], o[1], o[2], o[3]);
    }
}

extern "C" void kernel_launch(void* const* d_in, const int* in_sizes, int n_in,
                              void* d_out, int out_size, void* d_ws, size_t ws_size,
                              hipStream_t stream)
{
    const float* attrs   = (const float*)d_in[0];
    const float* pos     = (const float*)d_in[1];
    const int*   snd     = (const int*)d_in[2];
    const int*   rcv     = (const int*)d_in[3];
    const float* W_embed = (const float*)d_in[4];
    const float* atomE   = (const float*)d_in[5];
    const float* Wr0     = (const float*)d_in[6];
    const float* Wr1     = (const float*)d_in[7];
    const float* Wr2     = (const float*)d_in[8];
    const float* Wr3     = (const float*)d_in[9];
    const float* Wlin    = (const float*)d_in[10];
    const float* Wsc     = (const float*)d_in[11];
    const float* Wprod   = (const float*)d_in[12];
    const float* Wp      = (const float*)d_in[13];
    const float* w_ro1   = (const float*)d_in[14];
    const float* W_m1    = (const float*)d_in[15];
    const float* w_m2    = (const float*)d_in[16];

    const int N = in_sizes[1] / 3;
    const int E = in_sizes[2];

    float* energy = (float*)d_out;
    float* feats  = (float*)d_out + N;

    char* ws = (char*)d_ws;
    size_t off = 0;
    auto alloc = [&](size_t bytes) { void* p = ws + off; off = (off + bytes + 255) & ~(size_t)255; return p; };
    int*  deg    = (int*)alloc((size_t)N * 4);
    int*  cursor = (int*)alloc((size_t)N * 4);
    int*  rowptr = (int*)alloc((size_t)(N + 1) * 4);
    int*  gcnt   = (int*)alloc(256);
    int2* pairs  = (int2*)alloc((size_t)E * 8);
    int*  eS     = (int*)alloc((size_t)E * 4);
    int*  eT     = (int*)alloc((size_t)E * 4);
    int*  elem   = (int*)alloc((size_t)N * 4);
    float* h1    = (float*)alloc((size_t)N * Cdim * 4);
    _Float16* w_out = (_Float16*)(ws + off);

    k_node_init<<<(N + 255)/256, 256, 0, stream>>>(attrs, W_embed, atomE, elem, feats, energy, deg, gcnt, N);
    k_edge_zbl<<<(E + 255)/256, 256, 0, stream>>>(pos, snd, rcv, elem, energy, deg, pairs, gcnt, E);
    k_scan<<<1, 1024, 0, stream>>>(deg, rowptr, cursor, N);
    k_place<<<(E + 255)/256, 256, 0, stream>>>(pairs, gcnt, cursor, eS, eT);

    const int NBLK = (N + 31) / 32;
    for (int i = 0; i < 2; ++i) {
        k_h1<<<(N + 255)/256, 256, 0, stream>>>(feats, Wlin + i * Cdim * Cdim, h1, N);
        k_mlp<<<512, 256, 0, stream>>>(eS, eT, pos,
            Wr0 + i * NBES * HDIM, Wr1 + i * HDIM * HDIM,
            Wr2 + i * HDIM * HDIM, Wr3 + i * HDIM * 96,
            rowptr + N, w_out);
        k_gather<<<NBLK, 256, 0, stream>>>(rowptr, eS, pos, h1, w_out, feats, N);
        if (i == 0)
            k_epilogue<0><<<NBLK, 256, 0, stream>>>(feats, elem,
                Wprod + 0 * 3072, Wsc + 0 * 10240, Wp + 0 * 960,
                w_ro1, W_m1, w_m2, energy, N);
        else
            k_epilogue<1><<<NBLK, 256, 0, stream>>>(feats, elem,
                Wprod + 1 * 3072, Wsc + 1 * 10240, Wp + 1 * 960,
                w_ro1, W_m1, w_m2, energy, N);
    }
}

// Round 6
// 387.217 us; speedup vs baseline: 1.3463x; 1.3463x over previous
//
#include <hip/hip_runtime.h>
#include <math.h>

static constexpr int Cdim = 32;   // C
static constexpr int NBES = 8;    // NB
static constexpr int HDIM = 64;   // H
static constexpr int ZDIM = 10;   // Z

typedef _Float16 half8 __attribute__((ext_vector_type(8)));
typedef _Float16 half4 __attribute__((ext_vector_type(4)));
typedef float floatx4 __attribute__((ext_vector_type(4)));

__device__ __forceinline__ float silu_f(float x) {
    return x / (1.0f + __expf(-x));
}

// ---------------- node init: elem, h=W_embed[elem], energy=atomic_E, deg=0, pz2 ----------------
__global__ __launch_bounds__(256)
void k_node_init(const float* __restrict__ attrs, const float* __restrict__ W_embed,
                 const float* __restrict__ atomE, int* __restrict__ elem,
                 float* hOut /* feats base, stride 576 */, float* __restrict__ energy,
                 int* __restrict__ deg, float2* __restrict__ pz2, int N)
{
    int n = blockIdx.x * blockDim.x + threadIdx.x;
    if (n >= N) return;
    int e = 0; float best = -1.0f;
    #pragma unroll
    for (int z = 0; z < ZDIM; ++z) {
        float v = attrs[n * ZDIM + z];
        if (v > best) { best = v; e = z; }
    }
    elem[n] = e;
    #pragma unroll
    for (int c = 0; c < Cdim; ++c) hOut[(size_t)n * 576 + c] = W_embed[e * Cdim + c];
    energy[n] = atomE[e];
    deg[n] = 0;
    float zf = (float)(e + 1);
    pz2[n] = make_float2(zf, powf(zf, 0.23f));
}

// ---------------- filter: d^2 < 25 -> ballot mask + degree count ----------------
__global__ __launch_bounds__(256)
void k_filter(const float* __restrict__ pos, const int* __restrict__ snd,
              const int* __restrict__ rcv, unsigned long long* __restrict__ mask,
              int* __restrict__ deg, int E)
{
    int e = blockIdx.x * blockDim.x + threadIdx.x;
    int ec = min(e, E - 1);
    int s = snd[ec], t = rcv[ec];
    float dx = pos[3*t+0] - pos[3*s+0];
    float dy = pos[3*t+1] - pos[3*s+1];
    float dz = pos[3*t+2] - pos[3*s+2];
    float d2 = dx*dx + dy*dy + dz*dz;
    bool pred = (e < E) && (d2 < 25.0f);
    unsigned long long m = __ballot(pred ? 1 : 0);
    if ((threadIdx.x & 63) == 0) mask[e >> 6] = m;
    if (pred) atomicAdd(&deg[t], 1);
}

// ---------------- single-block exclusive scan ----------------
__global__ __launch_bounds__(1024)
void k_scan(const int* __restrict__ deg, int* __restrict__ rowptr,
            int* __restrict__ cursor, int N)
{
    __shared__ int wsum[16];
    __shared__ int chunk_base;
    int tid = threadIdx.x;
    int lane = tid & 63, w = tid >> 6;
    if (tid == 0) chunk_base = 0;
    __syncthreads();
    for (int base = 0; base < N; base += 1024) {
        int i = base + tid;
        int v = (i < N) ? deg[i] : 0;
        int s = v;
        #pragma unroll
        for (int d = 1; d < 64; d <<= 1) {
            int u = __shfl_up(s, d);
            if (lane >= d) s += u;
        }
        if (lane == 63) wsum[w] = s;
        __syncthreads();
        if (w == 0 && lane < 16) {
            int x = wsum[lane];
            #pragma unroll
            for (int d = 1; d < 16; d <<= 1) {
                int u = __shfl_up(x, d);
                if (lane >= d) x += u;
            }
            wsum[lane] = x;
        }
        __syncthreads();
        int wave_off = (w == 0) ? 0 : wsum[w - 1];
        int excl = chunk_base + wave_off + (s - v);
        if (i < N) { rowptr[i] = excl; cursor[i] = excl; }
        int total = wsum[15];
        __syncthreads();
        if (tid == 0) chunk_base += total;
        __syncthreads();
    }
    if (tid == 0) rowptr[N] = chunk_base;
}

// ---------------- place: mask-gated CSR fill (no distance recompute) ----------------
__global__ __launch_bounds__(256)
void k_place(const int* __restrict__ snd, const int* __restrict__ rcv,
             const unsigned long long* __restrict__ mask, int* __restrict__ cursor,
             int* __restrict__ eS, int* __restrict__ eT, int E)
{
    int e = blockIdx.x * blockDim.x + threadIdx.x;
    if (e >= E) return;
    if (!((mask[e >> 6] >> (e & 63)) & 1ull)) return;
    int t = rcv[e];
    int slot = atomicAdd(&cursor[t], 1);
    eS[slot] = snd[e];
    eT[slot] = t;
}

// ---------------- h1 = h @ Wlin[i] ----------------
__global__ __launch_bounds__(256)
void k_h1(const float* h, const float* __restrict__ Wlin,
          float* __restrict__ h1, int N)
{
    __shared__ float sW[Cdim * Cdim];
    for (int t = threadIdx.x; t < Cdim * Cdim; t += 256) sW[t] = Wlin[t];
    __syncthreads();
    int n = blockIdx.x * blockDim.x + threadIdx.x;
    if (n >= N) return;
    float hv[Cdim];
    #pragma unroll
    for (int c4 = 0; c4 < 8; ++c4) {
        float4 v = *(const float4*)(h + (size_t)n * 576 + c4 * 4);
        hv[c4*4+0] = v.x; hv[c4*4+1] = v.y; hv[c4*4+2] = v.z; hv[c4*4+3] = v.w;
    }
    float acc[Cdim];
    #pragma unroll
    for (int d = 0; d < Cdim; ++d) acc[d] = 0.f;
    #pragma unroll
    for (int c = 0; c < Cdim; ++c) {
        float hc = hv[c];
        #pragma unroll
        for (int d = 0; d < Cdim; ++d) acc[d] += hc * sW[c * Cdim + d];
    }
    #pragma unroll
    for (int d4 = 0; d4 < 8; ++d4)
        *(float4*)(h1 + (size_t)n * Cdim + d4 * 4) =
            make_float4(acc[d4*4], acc[d4*4+1], acc[d4*4+2], acc[d4*4+3]);
}

// ---------------- radial MLP via f16 MFMA (swapped operands -> packed stores) ----------------
__global__ __launch_bounds__(256, 2)
void k_mlp(const int* __restrict__ eS, const int* __restrict__ eT,
           const float* __restrict__ pos,
           const float* __restrict__ W0, const float* __restrict__ W1,
           const float* __restrict__ W2, const float* __restrict__ W3,
           const int* __restrict__ eactp, _Float16* __restrict__ w_out)
{
    __shared__ __align__(16) _Float16 sWt0[64*32];
    __shared__ __align__(16) _Float16 sWt1[64*64];
    __shared__ __align__(16) _Float16 sWt2[64*64];
    __shared__ __align__(16) _Float16 sWt3[96*64];
    __shared__ __align__(16) _Float16 sAct[4][64*64];

    for (int idx = threadIdx.x; idx < 64*32; idx += 256) {
        int n = idx >> 5, k = idx & 31;
        float v = (k < NBES) ? W0[k*64 + n] : 0.f;
        *(_Float16*)((char*)sWt0 + n*64 + ((k*2) ^ ((n&3)<<4))) = (_Float16)v;
    }
    for (int idx = threadIdx.x; idx < 64*64; idx += 256) {
        int k = idx >> 6, n = idx & 63;
        int byo = n*128 + ((k*2) ^ ((n&7)<<4));
        *(_Float16*)((char*)sWt1 + byo) = (_Float16)W1[idx];
        *(_Float16*)((char*)sWt2 + byo) = (_Float16)W2[idx];
    }
    for (int idx = threadIdx.x; idx < 64*96; idx += 256) {
        int k = idx / 96, n = idx - k*96;
        *(_Float16*)((char*)sWt3 + n*128 + ((k*2) ^ ((n&7)<<4))) = (_Float16)W3[idx];
    }
    __syncthreads();

    const int wid = threadIdx.x >> 6, lane = threadIdx.x & 63;
    const int l15 = lane & 15, lh = lane >> 4;
    const int Eact = *eactp;
    char* actc = (char*)sAct[wid];

    half8 w1f[4], w2f[4][2], w3f[4][2], w4f[6][2];
    #pragma unroll
    for (int nt = 0; nt < 4; ++nt) {
        int nn = nt*16 + l15;
        w1f[nt] = *(half8*)((char*)sWt0 + nn*64 + ((lh*16) ^ ((nn&3)<<4)));
        #pragma unroll
        for (int ks = 0; ks < 2; ++ks) {
            w2f[nt][ks] = *(half8*)((char*)sWt1 + nn*128 + ((ks*64 + lh*16) ^ ((nn&7)<<4)));
            w3f[nt][ks] = *(half8*)((char*)sWt2 + nn*128 + ((ks*64 + lh*16) ^ ((nn&7)<<4)));
        }
    }
    #pragma unroll
    for (int nt = 0; nt < 6; ++nt) {
        int nn = nt*16 + l15;
        #pragma unroll
        for (int ks = 0; ks < 2; ++ks)
            w4f[nt][ks] = *(half8*)((char*)sWt3 + nn*128 + ((ks*64 + lh*16) ^ ((nn&7)<<4)));
    }

    for (int c0 = (blockIdx.x*4 + wid)*64; c0 < Eact; c0 += gridDim.x*256) {
        int k = c0 + lane;
        bool okl = k < Eact;
        int kk = okl ? k : 0;
        int s = eS[kk], t = eT[kk];
        float dx = pos[3*t+0]-pos[3*s+0];
        float dy = pos[3*t+1]-pos[3*s+1];
        float dz = pos[3*t+2]-pos[3*s+2];
        float r  = sqrtf(dx*dx + dy*dy + dz*dz + 1e-12f);
        float inv_r = 1.0f / r;
        float u  = r / 5.0f;
        float u2 = u*u, u5 = u2*u2*u;
        float fcut = 1.0f - 21.0f*u5 + 35.0f*u5*u - 15.0f*u5*u2;
        float coef = 0.632455532f * inv_r * fcut;
        if (!okl) coef = 0.f;
        half8 rv;
        #pragma unroll
        for (int j = 0; j < NBES; ++j)
            rv[j] = (_Float16)(coef * __sinf((float)(j+1) * 0.628318531f * r));
        {
            int sw = (lane & 7) << 4;
            half8 zz = {};
            *(half8*)(actc + lane*128 + ( 0 ^ sw)) = rv;
            *(half8*)(actc + lane*128 + (16 ^ sw)) = zz;
            *(half8*)(actc + lane*128 + (32 ^ sw)) = zz;
            *(half8*)(actc + lane*128 + (48 ^ sw)) = zz;
        }
        __builtin_amdgcn_sched_barrier(0);

        // ---- L1 ----
        #pragma unroll
        for (int mt = 0; mt < 4; ++mt) {
            int rr = mt*16 + l15;
            int swz = (rr & 7) << 4;
            half8 act = *(half8*)(actc + rr*128 + ((lh*16) ^ swz));
            #pragma unroll
            for (int nt = 0; nt < 4; ++nt) {
                floatx4 z = {0.f,0.f,0.f,0.f};
                floatx4 d = __builtin_amdgcn_mfma_f32_16x16x32_f16(w1f[nt], act, z, 0,0,0);
                half4 pk;
                #pragma unroll
                for (int j = 0; j < 4; ++j) pk[j] = (_Float16)silu_f(d[j]);
                *(half4*)(actc + rr*128 + ((nt*32 + lh*8) ^ swz)) = pk;
            }
        }
        __builtin_amdgcn_sched_barrier(0);

        // ---- L2, L3 ----
        #pragma unroll
        for (int layer = 0; layer < 2; ++layer) {
            #pragma unroll
            for (int mt = 0; mt < 4; ++mt) {
                int rr = mt*16 + l15;
                int swz = (rr & 7) << 4;
                half8 a0 = *(half8*)(actc + rr*128 + ((      lh*16) ^ swz));
                half8 a1 = *(half8*)(actc + rr*128 + ((64 + lh*16) ^ swz));
                #pragma unroll
                for (int nt = 0; nt < 4; ++nt) {
                    floatx4 z = {0.f,0.f,0.f,0.f};
                    if (layer == 0) {
                        z = __builtin_amdgcn_mfma_f32_16x16x32_f16(w2f[nt][0], a0, z, 0,0,0);
                        z = __builtin_amdgcn_mfma_f32_16x16x32_f16(w2f[nt][1], a1, z, 0,0,0);
                    } else {
                        z = __builtin_amdgcn_mfma_f32_16x16x32_f16(w3f[nt][0], a0, z, 0,0,0);
                        z = __builtin_amdgcn_mfma_f32_16x16x32_f16(w3f[nt][1], a1, z, 0,0,0);
                    }
                    half4 pk;
                    #pragma unroll
                    for (int j = 0; j < 4; ++j) pk[j] = (_Float16)silu_f(z[j]);
                    *(half4*)(actc + rr*128 + ((nt*32 + lh*8) ^ swz)) = pk;
                }
            }
            __builtin_amdgcn_sched_barrier(0);
        }

        // ---- L4 -> packed global stores ----
        #pragma unroll
        for (int mt = 0; mt < 4; ++mt) {
            int rr = mt*16 + l15;
            int swz = (rr & 7) << 4;
            half8 a0 = *(half8*)(actc + rr*128 + ((      lh*16) ^ swz));
            half8 a1 = *(half8*)(actc + rr*128 + ((64 + lh*16) ^ swz));
            int e = c0 + rr;
            bool oke = e < Eact;
            #pragma unroll
            for (int nt = 0; nt < 6; ++nt) {
                floatx4 z = {0.f,0.f,0.f,0.f};
                z = __builtin_amdgcn_mfma_f32_16x16x32_f16(w4f[nt][0], a0, z, 0,0,0);
                z = __builtin_amdgcn_mfma_f32_16x16x32_f16(w4f[nt][1], a1, z, 0,0,0);
                half4 pk;
                #pragma unroll
                for (int j = 0; j < 4; ++j) pk[j] = (_Float16)z[j];
                if (oke)
                    *(half4*)(w_out + (size_t)e*96 + nt*16 + lh*4) = pk;
            }
        }
        __builtin_amdgcn_sched_barrier(0);
    }
}

// ---------------- gather: 8 lanes/node register segmented reduction (+ ZBL on iter 0) ----------------
template<int ITER>
__global__ __launch_bounds__(256)
void k_gather(const int* __restrict__ rowptr, const int* __restrict__ eS,
              const float* __restrict__ pos, const float2* __restrict__ pz2,
              const float* __restrict__ h1, const _Float16* __restrict__ w_out,
              float* __restrict__ feats, float* __restrict__ energy, int N)
{
    int g = threadIdx.x >> 3;
    int j = threadIdx.x & 7;
    int n = blockIdx.x * 32 + g;
    if (n >= N) return;
    int c0 = j * 4;

    float acc[9][4];
    #pragma unroll
    for (int m = 0; m < 9; ++m)
        #pragma unroll
        for (int q = 0; q < 4; ++q) acc[m][q] = 0.f;

    float px = pos[3*n+0], py = pos[3*n+1], pz = pos[3*n+2];
    float2 pn2 = pz2[n];
    float zacc = 0.f;
    int lo = rowptr[n], hi = rowptr[n+1];

    for (int k = lo; k < hi; ++k) {
        int s = eS[k];
        float dx = px - pos[3*s+0];
        float dy = py - pos[3*s+1];
        float dz = pz - pos[3*s+2];
        float r  = sqrtf(dx*dx + dy*dy + dz*dz + 1e-12f);
        float inv_r = 1.0f / r;
        float ux = dx*inv_r, uy = dy*inv_r, uz = dz*inv_r;
        const float s3 = 1.73205081f, s5 = 2.23606798f, s15 = 3.87298335f;
        float sh[9];
        sh[0] = 1.0f;
        sh[1] = s3 * ux; sh[2] = s3 * uy; sh[3] = s3 * uz;
        sh[4] = s15 * ux * uy; sh[5] = s15 * uy * uz;
        sh[6] = 0.5f * s5 * (3.0f * uz * uz - 1.0f);
        sh[7] = s15 * ux * uz;
        sh[8] = 0.5f * s15 * (ux * ux - uy * uy);

        if (ITER == 0) {
            float2 ps2 = pz2[s];
            float u  = r * 0.2f;
            float u2 = u*u, u5 = u2*u2*u;
            float fcut = 1.0f - 21.0f*u5 + 35.0f*u5*u - 15.0f*u5*u2;
            float xx = r * (ps2.y + pn2.y) * 2.134471718f;  // r / (0.4685/(zi^.23+zj^.23))
            float phi = 0.1818f*__expf(-3.2f*xx) + 0.5099f*__expf(-0.9423f*xx)
                      + 0.2802f*__expf(-0.4029f*xx) + 0.02817f*__expf(-0.2016f*xx);
            zacc += pn2.x * ps2.x * inv_r * phi * fcut;
        }

        const _Float16* wp = w_out + (size_t)k * 96 + c0;
        half4 w0v = *(const half4*)(wp);
        half4 w1v = *(const half4*)(wp + 32);
        half4 w2v = *(const half4*)(wp + 64);
        float4 hv = *(const float4*)(h1 + (size_t)s * Cdim + c0);
        float hb[4] = {hv.x, hv.y, hv.z, hv.w};

        #pragma unroll
        for (int q = 0; q < 4; ++q) {
            float m0 = hb[q] * (float)w0v[q];
            float m1 = hb[q] * (float)w1v[q];
            float m2 = hb[q] * (float)w2v[q];
            acc[0][q] += m0;
            acc[1][q] += sh[1] * m1;
            acc[2][q] += sh[2] * m1;
            acc[3][q] += sh[3] * m1;
            acc[4][q] += sh[4] * m2;
            acc[5][q] += sh[5] * m2;
            acc[6][q] += sh[6] * m2;
            acc[7][q] += sh[7] * m2;
            acc[8][q] += sh[8] * m2;
        }
    }

    if (ITER == 0 && j == 0) energy[n] += 7.1998f * zacc;   // 14.3996 * 0.5

    float* Ar = feats + (size_t)n * 576 + 288 + c0;
    #pragma unroll
    for (int m = 0; m < 9; ++m)
        *(float4*)(Ar + m * Cdim) = make_float4(acc[m][0], acc[m][1], acc[m][2], acc[m][3]);
}

// ---------------- fused epilogue: out_m + scalar channel + energy, 8 lanes/node ----------------
template<int ITER>
__global__ __launch_bounds__(256)
void k_epilogue(float* AO, const int* __restrict__ elem,
                const float* __restrict__ Wprod, const float* __restrict__ Wsc,
                const float* __restrict__ Wp, const float* __restrict__ w_ro1,
                const float* __restrict__ W_m1, const float* __restrict__ w_m2,
                float* __restrict__ energy, int N)
{
    __shared__ float sWp[3 * 1024];
    __shared__ float sM1[512];
    __shared__ float sm2[16];
    __shared__ float sro[32];
    __shared__ float sNode[32][321];

    for (int t = threadIdx.x; t < 3072; t += 256) sWp[t] = Wprod[t];
    for (int t = threadIdx.x; t < 512; t += 256) sM1[t] = W_m1[t];
    if (threadIdx.x < 16) sm2[threadIdx.x] = w_m2[threadIdx.x];
    if (threadIdx.x < 32) sro[threadIdx.x] = w_ro1[threadIdx.x];

    int nbase = blockIdx.x * 32;
    for (int t = threadIdx.x; t < 32 * 72; t += 256) {
        int g = t / 72, q = t - g * 72;
        int n = nbase + g;
        if (n < N)
            *(float4*)&sNode[g][q * 4] = *(const float4*)(AO + (size_t)n * 576 + 288 + q * 4);
    }
    for (int t = threadIdx.x; t < 32 * 8; t += 256) {
        int g = t / 8, q = t - g * 8;
        int n = nbase + g;
        if (n < N)
            *(float4*)&sNode[g][288 + q * 4] = *(const float4*)(AO + (size_t)n * 576 + q * 4);
    }
    __syncthreads();

    int g = threadIdx.x >> 3, j = threadIdx.x & 7, c0 = j * 4;
    int n = nbase + g;
    if (n >= N) return;
    int el = elem[n];
    const float* An = sNode[g];
    const int outslot = (ITER == 0) ? 0 : 288;

    float hs[4] = {0.f, 0.f, 0.f, 0.f};
    #pragma unroll 8
    for (int c = 0; c < 32; ++c) {
        float av = An[c] * 0.0625f;
        #pragma unroll
        for (int d = 0; d < 4; ++d) hs[d] += av * sWp[c * 32 + c0 + d];
    }
    const float* Ws = Wsc + (size_t)el * 1024;
    #pragma unroll 8
    for (int c = 0; c < 32; ++c) {
        float hc = An[288 + c];
        float4 wv = *(const float4*)(Ws + c * 32 + c0);
        hs[0] += hc * wv.x; hs[1] += hc * wv.y; hs[2] += hc * wv.z; hs[3] += hc * wv.w;
    }
    const float* wpb = Wp + el * 32;
    #pragma unroll
    for (int d = 0; d < 4; ++d) {
        float A = An[c0 + d] * 0.0625f, A2 = A * A;
        hs[d] += wpb[c0 + d] * A + wpb[320 + c0 + d] * A2 + wpb[640 + c0 + d] * (A2 * A);
    }

    float eadd;
    if (ITER == 0) {
        float acc = 0.f;
        #pragma unroll
        for (int d = 0; d < 4; ++d) acc += hs[d] * sro[c0 + d];
        acc += __shfl_xor(acc, 1); acc += __shfl_xor(acc, 2); acc += __shfl_xor(acc, 4);
        eadd = acc;
    } else {
        float tj[16];
        #pragma unroll
        for (int q = 0; q < 16; ++q) {
            float tv = 0.f;
            #pragma unroll
            for (int d = 0; d < 4; ++d) tv += hs[d] * sM1[(c0 + d) * 16 + q];
            tv += __shfl_xor(tv, 1); tv += __shfl_xor(tv, 2); tv += __shfl_xor(tv, 4);
            tj[q] = tv;
        }
        float acc = 0.f;
        #pragma unroll
        for (int q = 0; q < 16; ++q) acc += silu_f(tj[q]) * sm2[q];
        eadd = acc;
    }
    if (j == 0) energy[n] += eadd;

    *(float4*)(AO + (size_t)n * 576 + outslot + c0) = make_float4(hs[0], hs[1], hs[2], hs[3]);

    #pragma unroll
    for (int m = 1; m <= 8; ++m) {
        const float* wb = sWp + ((m <= 3) ? 1 : 2) * 1024;
        const float* Am = An + m * 32;
        float o[4] = {0.f, 0.f, 0.f, 0.f};
        #pragma unroll 8
        for (int c = 0; c < 32; ++c) {
            float av = Am[c] * 0.0625f;
            #pragma unroll
            for (int d = 0; d < 4; ++d) o[d] += av * wb[c * 32 + c0 + d];
        }
        *(float4*)(AO + (size_t)n * 576 + outslot + m * 32 + c0) = make_float4(o[0], o[1], o[2], o[3]);
    }
}

extern "C" void kernel_launch(void* const* d_in, const int* in_sizes, int n_in,
                              void* d_out, int out_size, void* d_ws, size_t ws_size,
                              hipStream_t stream)
{
    const float* attrs   = (const float*)d_in[0];
    const float* pos     = (const float*)d_in[1];
    const int*   snd     = (const int*)d_in[2];
    const int*   rcv     = (const int*)d_in[3];
    const float* W_embed = (const float*)d_in[4];
    const float* atomE   = (const float*)d_in[5];
    const float* Wr0     = (const float*)d_in[6];
    const float* Wr1     = (const float*)d_in[7];
    const float* Wr2     = (const float*)d_in[8];
    const float* Wr3     = (const float*)d_in[9];
    const float* Wlin    = (const float*)d_in[10];
    const float* Wsc     = (const float*)d_in[11];
    const float* Wprod   = (const float*)d_in[12];
    const float* Wp      = (const float*)d_in[13];
    const float* w_ro1   = (const float*)d_in[14];
    const float* W_m1    = (const float*)d_in[15];
    const float* w_m2    = (const float*)d_in[16];

    const int N = in_sizes[1] / 3;
    const int E = in_sizes[2];

    float* energy = (float*)d_out;
    float* feats  = (float*)d_out + N;

    char* ws = (char*)d_ws;
    size_t off = 0;
    auto alloc = [&](size_t bytes) { void* p = ws + off; off = (off + bytes + 255) & ~(size_t)255; return p; };
    int*  deg    = (int*)alloc((size_t)N * 4);
    int*  cursor = (int*)alloc((size_t)N * 4);
    int*  rowptr = (int*)alloc((size_t)(N + 1) * 4);
    unsigned long long* mask = (unsigned long long*)alloc((size_t)((E + 63) / 64) * 8);
    int*  eS     = (int*)alloc((size_t)E * 4);
    int*  eT     = (int*)alloc((size_t)E * 4);
    int*  elem   = (int*)alloc((size_t)N * 4);
    float2* pz2  = (float2*)alloc((size_t)N * 8);
    float* h1    = (float*)alloc((size_t)N * Cdim * 4);
    _Float16* w_out = (_Float16*)(ws + off);

    k_node_init<<<(N + 255)/256, 256, 0, stream>>>(attrs, W_embed, atomE, elem, feats, energy, deg, pz2, N);
    k_filter<<<(E + 255)/256, 256, 0, stream>>>(pos, snd, rcv, mask, deg, E);
    k_scan<<<1, 1024, 0, stream>>>(deg, rowptr, cursor, N);
    k_place<<<(E + 255)/256, 256, 0, stream>>>(snd, rcv, mask, cursor, eS, eT, E);

    const int NBLK = (N + 31) / 32;
    for (int i = 0; i < 2; ++i) {
        k_h1<<<(N + 255)/256, 256, 0, stream>>>(feats, Wlin + i * Cdim * Cdim, h1, N);
        k_mlp<<<512, 256, 0, stream>>>(eS, eT, pos,
            Wr0 + i * NBES * HDIM, Wr1 + i * HDIM * HDIM,
            Wr2 + i * HDIM * HDIM, Wr3 + i * HDIM * 96,
            rowptr + N, w_out);
        if (i == 0)
            k_gather<0><<<NBLK, 256, 0, stream>>>(rowptr, eS, pos, pz2, h1, w_out, feats, energy, N);
        else
            k_gather<1><<<NBLK, 256, 0, stream>>>(rowptr, eS, pos, pz2, h1, w_out, feats, energy, N);
        if (i == 0)
            k_epilogue<0><<<NBLK, 256, 0, stream>>>(feats, elem,
                Wprod + 0 * 3072, Wsc + 0 * 10240, Wp + 0 * 960,
                w_ro1, W_m1, w_m2, energy, N);
        else
            k_epilogue<1><<<NBLK, 256, 0, stream>>>(feats, elem,
                Wprod + 1 * 3072, Wsc + 1 * 10240, Wp + 1 * 960,
                w_ro1, W_m1, w_m2, energy, N);
    }
}

// Round 7
// 353.888 us; speedup vs baseline: 1.4731x; 1.0942x over previous
//
#include <hip/hip_runtime.h>
#include <math.h>

static constexpr int Cdim = 32;   // C
static constexpr int NBES = 8;    // NB
static constexpr int HDIM = 64;   // H
static constexpr int ZDIM = 10;   // Z

typedef _Float16 half8 __attribute__((ext_vector_type(8)));
typedef _Float16 half4 __attribute__((ext_vector_type(4)));
typedef float floatx4 __attribute__((ext_vector_type(4)));

__device__ __forceinline__ float silu_f(float x) {
    return x / (1.0f + __expf(-x));
}

// ---------------- node init: elem, h=W_embed[elem], energy=atomic_E, deg=0, pz2 ----------------
__global__ __launch_bounds__(256)
void k_node_init(const float* __restrict__ attrs, const float* __restrict__ W_embed,
                 const float* __restrict__ atomE, int* __restrict__ elem,
                 float* hOut /* feats base, stride 576 */, float* __restrict__ energy,
                 int* __restrict__ deg, float2* __restrict__ pz2, int N)
{
    int n = blockIdx.x * blockDim.x + threadIdx.x;
    if (n >= N) return;
    int e = 0; float best = -1.0f;
    #pragma unroll
    for (int z = 0; z < ZDIM; ++z) {
        float v = attrs[n * ZDIM + z];
        if (v > best) { best = v; e = z; }
    }
    elem[n] = e;
    #pragma unroll
    for (int c = 0; c < Cdim; ++c) hOut[(size_t)n * 576 + c] = W_embed[e * Cdim + c];
    energy[n] = atomE[e];
    deg[n] = 0;
    float zf = (float)(e + 1);
    pz2[n] = make_float2(zf, powf(zf, 0.23f));
}

// ---------------- filter: d^2 < 25 -> ballot mask + degree count ----------------
__global__ __launch_bounds__(256)
void k_filter(const float* __restrict__ pos, const int* __restrict__ snd,
              const int* __restrict__ rcv, unsigned long long* __restrict__ mask,
              int* __restrict__ deg, int E)
{
    int e = blockIdx.x * blockDim.x + threadIdx.x;
    int ec = min(e, E - 1);
    int s = snd[ec], t = rcv[ec];
    float dx = pos[3*t+0] - pos[3*s+0];
    float dy = pos[3*t+1] - pos[3*s+1];
    float dz = pos[3*t+2] - pos[3*s+2];
    float d2 = dx*dx + dy*dy + dz*dz;
    bool pred = (e < E) && (d2 < 25.0f);
    unsigned long long m = __ballot(pred ? 1 : 0);
    if ((threadIdx.x & 63) == 0) mask[e >> 6] = m;
    if (pred) atomicAdd(&deg[t], 1);
}

// ---------------- single-block exclusive scan ----------------
__global__ __launch_bounds__(1024)
void k_scan(const int* __restrict__ deg, int* __restrict__ rowptr,
            int* __restrict__ cursor, int N)
{
    __shared__ int wsum[16];
    __shared__ int chunk_base;
    int tid = threadIdx.x;
    int lane = tid & 63, w = tid >> 6;
    if (tid == 0) chunk_base = 0;
    __syncthreads();
    for (int base = 0; base < N; base += 1024) {
        int i = base + tid;
        int v = (i < N) ? deg[i] : 0;
        int s = v;
        #pragma unroll
        for (int d = 1; d < 64; d <<= 1) {
            int u = __shfl_up(s, d);
            if (lane >= d) s += u;
        }
        if (lane == 63) wsum[w] = s;
        __syncthreads();
        if (w == 0 && lane < 16) {
            int x = wsum[lane];
            #pragma unroll
            for (int d = 1; d < 16; d <<= 1) {
                int u = __shfl_up(x, d);
                if (lane >= d) x += u;
            }
            wsum[lane] = x;
        }
        __syncthreads();
        int wave_off = (w == 0) ? 0 : wsum[w - 1];
        int excl = chunk_base + wave_off + (s - v);
        if (i < N) { rowptr[i] = excl; cursor[i] = excl; }
        int total = wsum[15];
        __syncthreads();
        if (tid == 0) chunk_base += total;
        __syncthreads();
    }
    if (tid == 0) rowptr[N] = chunk_base;
}

// ---------------- place: mask-gated CSR fill ----------------
__global__ __launch_bounds__(256)
void k_place(const int* __restrict__ snd, const int* __restrict__ rcv,
             const unsigned long long* __restrict__ mask, int* __restrict__ cursor,
             int* __restrict__ eS, int* __restrict__ eT, int E)
{
    int e = blockIdx.x * blockDim.x + threadIdx.x;
    if (e >= E) return;
    if (!((mask[e >> 6] >> (e & 63)) & 1ull)) return;
    int t = rcv[e];
    int slot = atomicAdd(&cursor[t], 1);
    eS[slot] = snd[e];
    eT[slot] = t;
}

// ---------------- h1 = h @ Wlin[0] (iteration 0 only) ----------------
__global__ __launch_bounds__(256)
void k_h1(const float* h, const float* __restrict__ Wlin,
          float* __restrict__ h1, int N)
{
    __shared__ float sW[Cdim * Cdim];
    for (int t = threadIdx.x; t < Cdim * Cdim; t += 256) sW[t] = Wlin[t];
    __syncthreads();
    int n = blockIdx.x * blockDim.x + threadIdx.x;
    if (n >= N) return;
    float hv[Cdim];
    #pragma unroll
    for (int c4 = 0; c4 < 8; ++c4) {
        float4 v = *(const float4*)(h + (size_t)n * 576 + c4 * 4);
        hv[c4*4+0] = v.x; hv[c4*4+1] = v.y; hv[c4*4+2] = v.z; hv[c4*4+3] = v.w;
    }
    float acc[Cdim];
    #pragma unroll
    for (int d = 0; d < Cdim; ++d) acc[d] = 0.f;
    #pragma unroll
    for (int c = 0; c < Cdim; ++c) {
        float hc = hv[c];
        #pragma unroll
        for (int d = 0; d < Cdim; ++d) acc[d] += hc * sW[c * Cdim + d];
    }
    #pragma unroll
    for (int d4 = 0; d4 < 8; ++d4)
        *(float4*)(h1 + (size_t)n * Cdim + d4 * 4) =
            make_float4(acc[d4*4], acc[d4*4+1], acc[d4*4+2], acc[d4*4+3]);
}

// ---------------- radial MLP via f16 MFMA ----------------
__global__ __launch_bounds__(256, 2)
void k_mlp(const int* __restrict__ eS, const int* __restrict__ eT,
           const float* __restrict__ pos,
           const float* __restrict__ W0, const float* __restrict__ W1,
           const float* __restrict__ W2, const float* __restrict__ W3,
           const int* __restrict__ eactp, _Float16* __restrict__ w_out)
{
    __shared__ __align__(16) _Float16 sWt0[64*32];
    __shared__ __align__(16) _Float16 sWt1[64*64];
    __shared__ __align__(16) _Float16 sWt2[64*64];
    __shared__ __align__(16) _Float16 sWt3[96*64];
    __shared__ __align__(16) _Float16 sAct[4][64*64];

    for (int idx = threadIdx.x; idx < 64*32; idx += 256) {
        int n = idx >> 5, k = idx & 31;
        float v = (k < NBES) ? W0[k*64 + n] : 0.f;
        *(_Float16*)((char*)sWt0 + n*64 + ((k*2) ^ ((n&3)<<4))) = (_Float16)v;
    }
    for (int idx = threadIdx.x; idx < 64*64; idx += 256) {
        int k = idx >> 6, n = idx & 63;
        int byo = n*128 + ((k*2) ^ ((n&7)<<4));
        *(_Float16*)((char*)sWt1 + byo) = (_Float16)W1[idx];
        *(_Float16*)((char*)sWt2 + byo) = (_Float16)W2[idx];
    }
    for (int idx = threadIdx.x; idx < 64*96; idx += 256) {
        int k = idx / 96, n = idx - k*96;
        *(_Float16*)((char*)sWt3 + n*128 + ((k*2) ^ ((n&7)<<4))) = (_Float16)W3[idx];
    }
    __syncthreads();

    const int wid = threadIdx.x >> 6, lane = threadIdx.x & 63;
    const int l15 = lane & 15, lh = lane >> 4;
    const int Eact = *eactp;
    char* actc = (char*)sAct[wid];

    half8 w1f[4], w2f[4][2], w3f[4][2], w4f[6][2];
    #pragma unroll
    for (int nt = 0; nt < 4; ++nt) {
        int nn = nt*16 + l15;
        w1f[nt] = *(half8*)((char*)sWt0 + nn*64 + ((lh*16) ^ ((nn&3)<<4)));
        #pragma unroll
        for (int ks = 0; ks < 2; ++ks) {
            w2f[nt][ks] = *(half8*)((char*)sWt1 + nn*128 + ((ks*64 + lh*16) ^ ((nn&7)<<4)));
            w3f[nt][ks] = *(half8*)((char*)sWt2 + nn*128 + ((ks*64 + lh*16) ^ ((nn&7)<<4)));
        }
    }
    #pragma unroll
    for (int nt = 0; nt < 6; ++nt) {
        int nn = nt*16 + l15;
        #pragma unroll
        for (int ks = 0; ks < 2; ++ks)
            w4f[nt][ks] = *(half8*)((char*)sWt3 + nn*128 + ((ks*64 + lh*16) ^ ((nn&7)<<4)));
    }

    for (int c0 = (blockIdx.x*4 + wid)*64; c0 < Eact; c0 += gridDim.x*256) {
        int k = c0 + lane;
        bool okl = k < Eact;
        int kk = okl ? k : 0;
        int s = eS[kk], t = eT[kk];
        float dx = pos[3*t+0]-pos[3*s+0];
        float dy = pos[3*t+1]-pos[3*s+1];
        float dz = pos[3*t+2]-pos[3*s+2];
        float r  = sqrtf(dx*dx + dy*dy + dz*dz + 1e-12f);
        float inv_r = 1.0f / r;
        float u  = r / 5.0f;
        float u2 = u*u, u5 = u2*u2*u;
        float fcut = 1.0f - 21.0f*u5 + 35.0f*u5*u - 15.0f*u5*u2;
        float coef = 0.632455532f * inv_r * fcut;
        if (!okl) coef = 0.f;
        half8 rv;
        #pragma unroll
        for (int j = 0; j < NBES; ++j)
            rv[j] = (_Float16)(coef * __sinf((float)(j+1) * 0.628318531f * r));
        {
            int sw = (lane & 7) << 4;
            half8 zz = {};
            *(half8*)(actc + lane*128 + ( 0 ^ sw)) = rv;
            *(half8*)(actc + lane*128 + (16 ^ sw)) = zz;
            *(half8*)(actc + lane*128 + (32 ^ sw)) = zz;
            *(half8*)(actc + lane*128 + (48 ^ sw)) = zz;
        }
        __builtin_amdgcn_sched_barrier(0);

        // ---- L1 ----
        #pragma unroll
        for (int mt = 0; mt < 4; ++mt) {
            int rr = mt*16 + l15;
            int swz = (rr & 7) << 4;
            half8 act = *(half8*)(actc + rr*128 + ((lh*16) ^ swz));
            #pragma unroll
            for (int nt = 0; nt < 4; ++nt) {
                floatx4 z = {0.f,0.f,0.f,0.f};
                floatx4 d = __builtin_amdgcn_mfma_f32_16x16x32_f16(w1f[nt], act, z, 0,0,0);
                half4 pk;
                #pragma unroll
                for (int j = 0; j < 4; ++j) pk[j] = (_Float16)silu_f(d[j]);
                *(half4*)(actc + rr*128 + ((nt*32 + lh*8) ^ swz)) = pk;
            }
        }
        __builtin_amdgcn_sched_barrier(0);

        // ---- L2, L3 ----
        #pragma unroll
        for (int layer = 0; layer < 2; ++layer) {
            #pragma unroll
            for (int mt = 0; mt < 4; ++mt) {
                int rr = mt*16 + l15;
                int swz = (rr & 7) << 4;
                half8 a0 = *(half8*)(actc + rr*128 + ((      lh*16) ^ swz));
                half8 a1 = *(half8*)(actc + rr*128 + ((64 + lh*16) ^ swz));
                #pragma unroll
                for (int nt = 0; nt < 4; ++nt) {
                    floatx4 z = {0.f,0.f,0.f,0.f};
                    if (layer == 0) {
                        z = __builtin_amdgcn_mfma_f32_16x16x32_f16(w2f[nt][0], a0, z, 0,0,0);
                        z = __builtin_amdgcn_mfma_f32_16x16x32_f16(w2f[nt][1], a1, z, 0,0,0);
                    } else {
                        z = __builtin_amdgcn_mfma_f32_16x16x32_f16(w3f[nt][0], a0, z, 0,0,0);
                        z = __builtin_amdgcn_mfma_f32_16x16x32_f16(w3f[nt][1], a1, z, 0,0,0);
                    }
                    half4 pk;
                    #pragma unroll
                    for (int j = 0; j < 4; ++j) pk[j] = (_Float16)silu_f(z[j]);
                    *(half4*)(actc + rr*128 + ((nt*32 + lh*8) ^ swz)) = pk;
                }
            }
            __builtin_amdgcn_sched_barrier(0);
        }

        // ---- L4 -> packed global stores ----
        #pragma unroll
        for (int mt = 0; mt < 4; ++mt) {
            int rr = mt*16 + l15;
            int swz = (rr & 7) << 4;
            half8 a0 = *(half8*)(actc + rr*128 + ((      lh*16) ^ swz));
            half8 a1 = *(half8*)(actc + rr*128 + ((64 + lh*16) ^ swz));
            int e = c0 + rr;
            bool oke = e < Eact;
            #pragma unroll
            for (int nt = 0; nt < 6; ++nt) {
                floatx4 z = {0.f,0.f,0.f,0.f};
                z = __builtin_amdgcn_mfma_f32_16x16x32_f16(w4f[nt][0], a0, z, 0,0,0);
                z = __builtin_amdgcn_mfma_f32_16x16x32_f16(w4f[nt][1], a1, z, 0,0,0);
                half4 pk;
                #pragma unroll
                for (int j = 0; j < 4; ++j) pk[j] = (_Float16)z[j];
                if (oke)
                    *(half4*)(w_out + (size_t)e*96 + nt*16 + lh*4) = pk;
            }
        }
        __builtin_amdgcn_sched_barrier(0);
    }
}

// ---------------- FUSED gather + epilogue (+ ZBL iter0, + h1-for-iter1) ----------------
template<int ITER>
__global__ __launch_bounds__(256)
void k_gather_epi(const int* __restrict__ rowptr, const int* __restrict__ eS,
                  const float* __restrict__ pos, const float2* __restrict__ pz2,
                  const float* __restrict__ h1, const _Float16* __restrict__ w_out,
                  float* AO, const int* __restrict__ elem,
                  const float* __restrict__ Wprod, const float* __restrict__ Wsc,
                  const float* __restrict__ Wp, const float* __restrict__ w_ro1,
                  const float* __restrict__ W_m1, const float* __restrict__ w_m2,
                  const float* __restrict__ Wlin_next, float* __restrict__ h1_next,
                  float* __restrict__ energy, int N)
{
    __shared__ float sWp[3 * 1024];
    __shared__ float sM1[512];
    __shared__ float sm2[16];
    __shared__ float sro[32];
    __shared__ float sWl[(ITER == 0) ? 1024 : 16];
    __shared__ float sNode[32][321];   // [A 0..287 | h 288..319]

    for (int t = threadIdx.x; t < 3072; t += 256) sWp[t] = Wprod[t];
    for (int t = threadIdx.x; t < 512; t += 256) sM1[t] = W_m1[t];
    if (ITER == 0)
        for (int t = threadIdx.x; t < 1024; t += 256) sWl[t] = Wlin_next[t];
    if (threadIdx.x < 16) sm2[threadIdx.x] = w_m2[threadIdx.x];
    if (threadIdx.x < 32) sro[threadIdx.x] = w_ro1[threadIdx.x];

    int g = threadIdx.x >> 3, j = threadIdx.x & 7, c0 = j * 4;
    int n = blockIdx.x * 32 + g;
    bool valid = (n < N);

    // ---- register gather over this node's CSR range ----
    float acc[9][4];
    #pragma unroll
    for (int m = 0; m < 9; ++m)
        #pragma unroll
        for (int q = 0; q < 4; ++q) acc[m][q] = 0.f;
    float zacc = 0.f;

    if (valid) {
        float px = pos[3*n+0], py = pos[3*n+1], pz = pos[3*n+2];
        float2 pn2 = pz2[n];
        int lo = rowptr[n], hi = rowptr[n+1];
        for (int k = lo; k < hi; ++k) {
            int s = eS[k];
            float dx = px - pos[3*s+0];
            float dy = py - pos[3*s+1];
            float dz = pz - pos[3*s+2];
            float r  = sqrtf(dx*dx + dy*dy + dz*dz + 1e-12f);
            float inv_r = 1.0f / r;
            float ux = dx*inv_r, uy = dy*inv_r, uz = dz*inv_r;
            const float s3 = 1.73205081f, s5 = 2.23606798f, s15 = 3.87298335f;
            float sh[9];
            sh[0] = 1.0f;
            sh[1] = s3 * ux; sh[2] = s3 * uy; sh[3] = s3 * uz;
            sh[4] = s15 * ux * uy; sh[5] = s15 * uy * uz;
            sh[6] = 0.5f * s5 * (3.0f * uz * uz - 1.0f);
            sh[7] = s15 * ux * uz;
            sh[8] = 0.5f * s15 * (ux * ux - uy * uy);

            if (ITER == 0) {
                float2 ps2 = pz2[s];
                float u  = r * 0.2f;
                float u2 = u*u, u5 = u2*u2*u;
                float fcut = 1.0f - 21.0f*u5 + 35.0f*u5*u - 15.0f*u5*u2;
                float xx = r * (ps2.y + pn2.y) * 2.134471718f;
                float phi = 0.1818f*__expf(-3.2f*xx) + 0.5099f*__expf(-0.9423f*xx)
                          + 0.2802f*__expf(-0.4029f*xx) + 0.02817f*__expf(-0.2016f*xx);
                zacc += pn2.x * ps2.x * inv_r * phi * fcut;
            }

            const _Float16* wp = w_out + (size_t)k * 96 + c0;
            half4 w0v = *(const half4*)(wp);
            half4 w1v = *(const half4*)(wp + 32);
            half4 w2v = *(const half4*)(wp + 64);
            float4 hv = *(const float4*)(h1 + (size_t)s * Cdim + c0);
            float hb[4] = {hv.x, hv.y, hv.z, hv.w};

            #pragma unroll
            for (int q = 0; q < 4; ++q) {
                float m0 = hb[q] * (float)w0v[q];
                float m1 = hb[q] * (float)w1v[q];
                float m2 = hb[q] * (float)w2v[q];
                acc[0][q] += m0;
                acc[1][q] += sh[1] * m1;
                acc[2][q] += sh[2] * m1;
                acc[3][q] += sh[3] * m1;
                acc[4][q] += sh[4] * m2;
                acc[5][q] += sh[5] * m2;
                acc[6][q] += sh[6] * m2;
                acc[7][q] += sh[7] * m2;
                acc[8][q] += sh[8] * m2;
            }
        }
        // stage A (raw) and h into this node's LDS row
        *(float4*)&sNode[g][288 + c0] = *(const float4*)(AO + (size_t)n * 576 + c0);
        #pragma unroll
        for (int m = 0; m < 9; ++m)
            *(float4*)&sNode[g][m * 32 + c0] =
                make_float4(acc[m][0], acc[m][1], acc[m][2], acc[m][3]);
    }
    __syncthreads();

    // ---- epilogue ----
    const float* An = sNode[g];
    const int outslot = (ITER == 0) ? 0 : 288;
    float hs[4] = {0.f, 0.f, 0.f, 0.f};

    if (valid) {
        int el = elem[n];
        #pragma unroll 8
        for (int c = 0; c < 32; ++c) {
            float av = An[c] * 0.0625f;
            #pragma unroll
            for (int d = 0; d < 4; ++d) hs[d] += av * sWp[c * 32 + c0 + d];
        }
        const float* Ws = Wsc + (size_t)el * 1024;
        #pragma unroll 8
        for (int c = 0; c < 32; ++c) {
            float hc = An[288 + c];
            float4 wv = *(const float4*)(Ws + c * 32 + c0);
            hs[0] += hc * wv.x; hs[1] += hc * wv.y; hs[2] += hc * wv.z; hs[3] += hc * wv.w;
        }
        const float* wpb = Wp + el * 32;
        #pragma unroll
        for (int d = 0; d < 4; ++d) {
            float A = An[c0 + d] * 0.0625f, A2 = A * A;
            hs[d] += wpb[c0 + d] * A + wpb[320 + c0 + d] * A2 + wpb[640 + c0 + d] * (A2 * A);
        }

        float eadd;
        if (ITER == 0) {
            float a = 0.f;
            #pragma unroll
            for (int d = 0; d < 4; ++d) a += hs[d] * sro[c0 + d];
            a += __shfl_xor(a, 1); a += __shfl_xor(a, 2); a += __shfl_xor(a, 4);
            eadd = a + 7.1998f * zacc;
        } else {
            float tj[16];
            #pragma unroll
            for (int q = 0; q < 16; ++q) {
                float tv = 0.f;
                #pragma unroll
                for (int d = 0; d < 4; ++d) tv += hs[d] * sM1[(c0 + d) * 16 + q];
                tv += __shfl_xor(tv, 1); tv += __shfl_xor(tv, 2); tv += __shfl_xor(tv, 4);
                tj[q] = tv;
            }
            float a = 0.f;
            #pragma unroll
            for (int q = 0; q < 16; ++q) a += silu_f(tj[q]) * sm2[q];
            eadd = a;
        }
        if (j == 0) energy[n] += eadd;

        *(float4*)(AO + (size_t)n * 576 + outslot + c0) = make_float4(hs[0], hs[1], hs[2], hs[3]);

        #pragma unroll
        for (int m = 1; m <= 8; ++m) {
            const float* wb = sWp + ((m <= 3) ? 1 : 2) * 1024;
            const float* Am = An + m * 32;
            float o[4] = {0.f, 0.f, 0.f, 0.f};
            #pragma unroll 8
            for (int c = 0; c < 32; ++c) {
                float av = Am[c] * 0.0625f;
                #pragma unroll
                for (int d = 0; d < 4; ++d) o[d] += av * wb[c * 32 + c0 + d];
            }
            *(float4*)(AO + (size_t)n * 576 + outslot + m * 32 + c0) =
                make_float4(o[0], o[1], o[2], o[3]);
        }
    }

    // ---- ITER 0: compute h1 for iteration 1 from the fresh h (= hs) ----
    if (ITER == 0) {
        __syncthreads();   // all lanes done reading An[288..] (old h)
        if (valid)
            *(float4*)&sNode[g][288 + c0] = make_float4(hs[0], hs[1], hs[2], hs[3]);
        __syncthreads();
        if (valid) {
            float o[4] = {0.f, 0.f, 0.f, 0.f};
            #pragma unroll 8
            for (int c = 0; c < 32; ++c) {
                float hc = sNode[g][288 + c];
                #pragma unroll
                for (int d = 0; d < 4; ++d) o[d] += hc * sWl[c * 32 + c0 + d];
            }
            *(float4*)(h1_next + (size_t)n * Cdim + c0) = make_float4(o[0], o[1], o[2], o[3]);
        }
    }
}

extern "C" void kernel_launch(void* const* d_in, const int* in_sizes, int n_in,
                              void* d_out, int out_size, void* d_ws, size_t ws_size,
                              hipStream_t stream)
{
    const float* attrs   = (const float*)d_in[0];
    const float* pos     = (const float*)d_in[1];
    const int*   snd     = (const int*)d_in[2];
    const int*   rcv     = (const int*)d_in[3];
    const float* W_embed = (const float*)d_in[4];
    const float* atomE   = (const float*)d_in[5];
    const float* Wr0     = (const float*)d_in[6];
    const float* Wr1     = (const float*)d_in[7];
    const float* Wr2     = (const float*)d_in[8];
    const float* Wr3     = (const float*)d_in[9];
    const float* Wlin    = (const float*)d_in[10];
    const float* Wsc     = (const float*)d_in[11];
    const float* Wprod   = (const float*)d_in[12];
    const float* Wp      = (const float*)d_in[13];
    const float* w_ro1   = (const float*)d_in[14];
    const float* W_m1    = (const float*)d_in[15];
    const float* w_m2    = (const float*)d_in[16];

    const int N = in_sizes[1] / 3;
    const int E = in_sizes[2];

    float* energy = (float*)d_out;
    float* feats  = (float*)d_out + N;

    char* ws = (char*)d_ws;
    size_t off = 0;
    auto alloc = [&](size_t bytes) { void* p = ws + off; off = (off + bytes + 255) & ~(size_t)255; return p; };
    int*  deg    = (int*)alloc((size_t)N * 4);
    int*  cursor = (int*)alloc((size_t)N * 4);
    int*  rowptr = (int*)alloc((size_t)(N + 1) * 4);
    unsigned long long* mask = (unsigned long long*)alloc((size_t)((E + 63) / 64) * 8);
    int*  eS     = (int*)alloc((size_t)E * 4);
    int*  eT     = (int*)alloc((size_t)E * 4);
    int*  elem   = (int*)alloc((size_t)N * 4);
    float2* pz2  = (float2*)alloc((size_t)N * 8);
    float* h1a   = (float*)alloc((size_t)N * Cdim * 4);
    float* h1b   = (float*)alloc((size_t)N * Cdim * 4);
    _Float16* w_out = (_Float16*)(ws + off);

    k_node_init<<<(N + 255)/256, 256, 0, stream>>>(attrs, W_embed, atomE, elem, feats, energy, deg, pz2, N);
    k_filter<<<(E + 255)/256, 256, 0, stream>>>(pos, snd, rcv, mask, deg, E);
    k_scan<<<1, 1024, 0, stream>>>(deg, rowptr, cursor, N);
    k_place<<<(E + 255)/256, 256, 0, stream>>>(snd, rcv, mask, cursor, eS, eT, E);
    k_h1<<<(N + 255)/256, 256, 0, stream>>>(feats, Wlin, h1a, N);

    const int NBLK = (N + 31) / 32;

    // ---- iteration 0 ----
    k_mlp<<<512, 256, 0, stream>>>(eS, eT, pos,
        Wr0, Wr1, Wr2, Wr3, rowptr + N, w_out);
    k_gather_epi<0><<<NBLK, 256, 0, stream>>>(rowptr, eS, pos, pz2, h1a, w_out,
        feats, elem, Wprod, Wsc, Wp, w_ro1, W_m1, w_m2,
        Wlin + 1024, h1b, energy, N);

    // ---- iteration 1 ----
    k_mlp<<<512, 256, 0, stream>>>(eS, eT, pos,
        Wr0 + NBES * HDIM, Wr1 + HDIM * HDIM, Wr2 + HDIM * HDIM, Wr3 + HDIM * 96,
        rowptr + N, w_out);
    k_gather_epi<1><<<NBLK, 256, 0, stream>>>(rowptr, eS, pos, pz2, h1b, w_out,
        feats, elem, Wprod + 3072, Wsc + 10240, Wp + 960, w_ro1, W_m1, w_m2,
        Wlin, h1b, energy, N);
}

// Round 8
// 341.573 us; speedup vs baseline: 1.5263x; 1.0361x over previous
//
#include <hip/hip_runtime.h>
#include <math.h>

static constexpr int Cdim = 32;   // C
static constexpr int NBES = 8;    // NB
static constexpr int HDIM = 64;   // H
static constexpr int ZDIM = 10;   // Z

typedef _Float16 half8 __attribute__((ext_vector_type(8)));
typedef _Float16 half4 __attribute__((ext_vector_type(4)));
typedef float floatx4 __attribute__((ext_vector_type(4)));

__device__ __forceinline__ float silu_f(float x) {
    return x / (1.0f + __expf(-x));
}

__device__ __forceinline__ float4 shfl4(float4 v, int src) {
    return make_float4(__shfl(v.x, src), __shfl(v.y, src),
                       __shfl(v.z, src), __shfl(v.w, src));
}

// ---------------- node init: elem, h=W_embed[elem], energy, deg=0, pos4 ----------------
__global__ __launch_bounds__(256)
void k_node_init(const float* __restrict__ attrs, const float* __restrict__ pos,
                 const float* __restrict__ W_embed, const float* __restrict__ atomE,
                 int* __restrict__ elem, float* hOut /* feats base, stride 576 */,
                 float* __restrict__ energy, int* __restrict__ deg,
                 float4* __restrict__ pos4, int N)
{
    int n = blockIdx.x * blockDim.x + threadIdx.x;
    if (n >= N) return;
    int e = 0; float best = -1.0f;
    #pragma unroll
    for (int z = 0; z < ZDIM; ++z) {
        float v = attrs[n * ZDIM + z];
        if (v > best) { best = v; e = z; }
    }
    elem[n] = e;
    #pragma unroll
    for (int c = 0; c < Cdim; ++c) hOut[(size_t)n * 576 + c] = W_embed[e * Cdim + c];
    energy[n] = atomE[e];
    deg[n] = 0;
    float zf = (float)(e + 1);
    pos4[n] = make_float4(pos[3*n+0], pos[3*n+1], pos[3*n+2],
                          4.0f * zf + powf(zf, 0.23f));
}

// ---------------- filter: d^2 < 25 -> ballot mask + degree count ----------------
__global__ __launch_bounds__(256)
void k_filter(const float4* __restrict__ pos4, const int* __restrict__ snd,
              const int* __restrict__ rcv, unsigned long long* __restrict__ mask,
              int* __restrict__ deg, int E)
{
    int e = blockIdx.x * blockDim.x + threadIdx.x;
    int ec = min(e, E - 1);
    int s = snd[ec], t = rcv[ec];
    float4 pt = pos4[t], ps = pos4[s];
    float dx = pt.x - ps.x, dy = pt.y - ps.y, dz = pt.z - ps.z;
    float d2 = dx*dx + dy*dy + dz*dz;
    bool pred = (e < E) && (d2 < 25.0f);
    unsigned long long m = __ballot(pred ? 1 : 0);
    if ((threadIdx.x & 63) == 0) mask[e >> 6] = m;
    if (pred) atomicAdd(&deg[t], 1);
}

// ---------------- single-block exclusive scan ----------------
__global__ __launch_bounds__(1024)
void k_scan(const int* __restrict__ deg, int* __restrict__ rowptr,
            int* __restrict__ cursor, int N)
{
    __shared__ int wsum[16];
    __shared__ int chunk_base;
    int tid = threadIdx.x;
    int lane = tid & 63, w = tid >> 6;
    if (tid == 0) chunk_base = 0;
    __syncthreads();
    for (int base = 0; base < N; base += 1024) {
        int i = base + tid;
        int v = (i < N) ? deg[i] : 0;
        int s = v;
        #pragma unroll
        for (int d = 1; d < 64; d <<= 1) {
            int u = __shfl_up(s, d);
            if (lane >= d) s += u;
        }
        if (lane == 63) wsum[w] = s;
        __syncthreads();
        if (w == 0 && lane < 16) {
            int x = wsum[lane];
            #pragma unroll
            for (int d = 1; d < 16; d <<= 1) {
                int u = __shfl_up(x, d);
                if (lane >= d) x += u;
            }
            wsum[lane] = x;
        }
        __syncthreads();
        int wave_off = (w == 0) ? 0 : wsum[w - 1];
        int excl = chunk_base + wave_off + (s - v);
        if (i < N) { rowptr[i] = excl; cursor[i] = excl; }
        int total = wsum[15];
        __syncthreads();
        if (tid == 0) chunk_base += total;
        __syncthreads();
    }
    if (tid == 0) rowptr[N] = chunk_base;
}

// ---------------- place: mask-gated CSR fill ----------------
__global__ __launch_bounds__(256)
void k_place(const int* __restrict__ snd, const int* __restrict__ rcv,
             const unsigned long long* __restrict__ mask, int* __restrict__ cursor,
             int* __restrict__ eS, int* __restrict__ eT, int E)
{
    int e = blockIdx.x * blockDim.x + threadIdx.x;
    if (e >= E) return;
    if (!((mask[e >> 6] >> (e & 63)) & 1ull)) return;
    int t = rcv[e];
    int slot = atomicAdd(&cursor[t], 1);
    eS[slot] = snd[e];
    eT[slot] = t;
}

// ---------------- h1 = h @ Wlin[0] (iteration 0 only) ----------------
__global__ __launch_bounds__(256)
void k_h1(const float* h, const float* __restrict__ Wlin,
          float* __restrict__ h1, int N)
{
    __shared__ float sW[Cdim * Cdim];
    for (int t = threadIdx.x; t < Cdim * Cdim; t += 256) sW[t] = Wlin[t];
    __syncthreads();
    int n = blockIdx.x * blockDim.x + threadIdx.x;
    if (n >= N) return;
    float hv[Cdim];
    #pragma unroll
    for (int c4 = 0; c4 < 8; ++c4) {
        float4 v = *(const float4*)(h + (size_t)n * 576 + c4 * 4);
        hv[c4*4+0] = v.x; hv[c4*4+1] = v.y; hv[c4*4+2] = v.z; hv[c4*4+3] = v.w;
    }
    float acc[Cdim];
    #pragma unroll
    for (int d = 0; d < Cdim; ++d) acc[d] = 0.f;
    #pragma unroll
    for (int c = 0; c < Cdim; ++c) {
        float hc = hv[c];
        #pragma unroll
        for (int d = 0; d < Cdim; ++d) acc[d] += hc * sW[c * Cdim + d];
    }
    #pragma unroll
    for (int d4 = 0; d4 < 8; ++d4)
        *(float4*)(h1 + (size_t)n * Cdim + d4 * 4) =
            make_float4(acc[d4*4], acc[d4*4+1], acc[d4*4+2], acc[d4*4+3]);
}

// ---------------- radial MLP via f16 MFMA ----------------
__global__ __launch_bounds__(256, 2)
void k_mlp(const int* __restrict__ eS, const int* __restrict__ eT,
           const float4* __restrict__ pos4,
           const float* __restrict__ W0, const float* __restrict__ W1,
           const float* __restrict__ W2, const float* __restrict__ W3,
           const int* __restrict__ eactp, _Float16* __restrict__ w_out)
{
    __shared__ __align__(16) _Float16 sWt0[64*32];
    __shared__ __align__(16) _Float16 sWt1[64*64];
    __shared__ __align__(16) _Float16 sWt2[64*64];
    __shared__ __align__(16) _Float16 sWt3[96*64];
    __shared__ __align__(16) _Float16 sAct[4][64*64];

    for (int idx = threadIdx.x; idx < 64*32; idx += 256) {
        int n = idx >> 5, k = idx & 31;
        float v = (k < NBES) ? W0[k*64 + n] : 0.f;
        *(_Float16*)((char*)sWt0 + n*64 + ((k*2) ^ ((n&3)<<4))) = (_Float16)v;
    }
    for (int idx = threadIdx.x; idx < 64*64; idx += 256) {
        int k = idx >> 6, n = idx & 63;
        int byo = n*128 + ((k*2) ^ ((n&7)<<4));
        *(_Float16*)((char*)sWt1 + byo) = (_Float16)W1[idx];
        *(_Float16*)((char*)sWt2 + byo) = (_Float16)W2[idx];
    }
    for (int idx = threadIdx.x; idx < 64*96; idx += 256) {
        int k = idx / 96, n = idx - k*96;
        *(_Float16*)((char*)sWt3 + n*128 + ((k*2) ^ ((n&7)<<4))) = (_Float16)W3[idx];
    }
    __syncthreads();

    const int wid = threadIdx.x >> 6, lane = threadIdx.x & 63;
    const int l15 = lane & 15, lh = lane >> 4;
    const int Eact = *eactp;
    char* actc = (char*)sAct[wid];

    half8 w1f[4], w2f[4][2], w3f[4][2], w4f[6][2];
    #pragma unroll
    for (int nt = 0; nt < 4; ++nt) {
        int nn = nt*16 + l15;
        w1f[nt] = *(half8*)((char*)sWt0 + nn*64 + ((lh*16) ^ ((nn&3)<<4)));
        #pragma unroll
        for (int ks = 0; ks < 2; ++ks) {
            w2f[nt][ks] = *(half8*)((char*)sWt1 + nn*128 + ((ks*64 + lh*16) ^ ((nn&7)<<4)));
            w3f[nt][ks] = *(half8*)((char*)sWt2 + nn*128 + ((ks*64 + lh*16) ^ ((nn&7)<<4)));
        }
    }
    #pragma unroll
    for (int nt = 0; nt < 6; ++nt) {
        int nn = nt*16 + l15;
        #pragma unroll
        for (int ks = 0; ks < 2; ++ks)
            w4f[nt][ks] = *(half8*)((char*)sWt3 + nn*128 + ((ks*64 + lh*16) ^ ((nn&7)<<4)));
    }

    for (int c0 = (blockIdx.x*4 + wid)*64; c0 < Eact; c0 += gridDim.x*256) {
        int k = c0 + lane;
        bool okl = k < Eact;
        int kk = okl ? k : 0;
        int s = eS[kk], t = eT[kk];
        float4 pt = pos4[t], ps = pos4[s];
        float dx = pt.x - ps.x, dy = pt.y - ps.y, dz = pt.z - ps.z;
        float r  = sqrtf(dx*dx + dy*dy + dz*dz + 1e-12f);
        float inv_r = 1.0f / r;
        float u  = r / 5.0f;
        float u2 = u*u, u5 = u2*u2*u;
        float fcut = 1.0f - 21.0f*u5 + 35.0f*u5*u - 15.0f*u5*u2;
        float coef = 0.632455532f * inv_r * fcut;
        if (!okl) coef = 0.f;
        half8 rv;
        #pragma unroll
        for (int j = 0; j < NBES; ++j)
            rv[j] = (_Float16)(coef * __sinf((float)(j+1) * 0.628318531f * r));
        {
            int sw = (lane & 7) << 4;
            half8 zz = {};
            *(half8*)(actc + lane*128 + ( 0 ^ sw)) = rv;
            *(half8*)(actc + lane*128 + (16 ^ sw)) = zz;
            *(half8*)(actc + lane*128 + (32 ^ sw)) = zz;
            *(half8*)(actc + lane*128 + (48 ^ sw)) = zz;
        }
        __builtin_amdgcn_sched_barrier(0);

        // ---- L1 ----
        #pragma unroll
        for (int mt = 0; mt < 4; ++mt) {
            int rr = mt*16 + l15;
            int swz = (rr & 7) << 4;
            half8 act = *(half8*)(actc + rr*128 + ((lh*16) ^ swz));
            #pragma unroll
            for (int nt = 0; nt < 4; ++nt) {
                floatx4 z = {0.f,0.f,0.f,0.f};
                floatx4 d = __builtin_amdgcn_mfma_f32_16x16x32_f16(w1f[nt], act, z, 0,0,0);
                half4 pk;
                #pragma unroll
                for (int j = 0; j < 4; ++j) pk[j] = (_Float16)silu_f(d[j]);
                *(half4*)(actc + rr*128 + ((nt*32 + lh*8) ^ swz)) = pk;
            }
        }
        __builtin_amdgcn_sched_barrier(0);

        // ---- L2, L3 ----
        #pragma unroll
        for (int layer = 0; layer < 2; ++layer) {
            #pragma unroll
            for (int mt = 0; mt < 4; ++mt) {
                int rr = mt*16 + l15;
                int swz = (rr & 7) << 4;
                half8 a0 = *(half8*)(actc + rr*128 + ((      lh*16) ^ swz));
                half8 a1 = *(half8*)(actc + rr*128 + ((64 + lh*16) ^ swz));
                #pragma unroll
                for (int nt = 0; nt < 4; ++nt) {
                    floatx4 z = {0.f,0.f,0.f,0.f};
                    if (layer == 0) {
                        z = __builtin_amdgcn_mfma_f32_16x16x32_f16(w2f[nt][0], a0, z, 0,0,0);
                        z = __builtin_amdgcn_mfma_f32_16x16x32_f16(w2f[nt][1], a1, z, 0,0,0);
                    } else {
                        z = __builtin_amdgcn_mfma_f32_16x16x32_f16(w3f[nt][0], a0, z, 0,0,0);
                        z = __builtin_amdgcn_mfma_f32_16x16x32_f16(w3f[nt][1], a1, z, 0,0,0);
                    }
                    half4 pk;
                    #pragma unroll
                    for (int j = 0; j < 4; ++j) pk[j] = (_Float16)silu_f(z[j]);
                    *(half4*)(actc + rr*128 + ((nt*32 + lh*8) ^ swz)) = pk;
                }
            }
            __builtin_amdgcn_sched_barrier(0);
        }

        // ---- L4 -> packed global stores ----
        #pragma unroll
        for (int mt = 0; mt < 4; ++mt) {
            int rr = mt*16 + l15;
            int swz = (rr & 7) << 4;
            half8 a0 = *(half8*)(actc + rr*128 + ((      lh*16) ^ swz));
            half8 a1 = *(half8*)(actc + rr*128 + ((64 + lh*16) ^ swz));
            int e = c0 + rr;
            bool oke = e < Eact;
            #pragma unroll
            for (int nt = 0; nt < 6; ++nt) {
                floatx4 z = {0.f,0.f,0.f,0.f};
                z = __builtin_amdgcn_mfma_f32_16x16x32_f16(w4f[nt][0], a0, z, 0,0,0);
                z = __builtin_amdgcn_mfma_f32_16x16x32_f16(w4f[nt][1], a1, z, 0,0,0);
                half4 pk;
                #pragma unroll
                for (int j = 0; j < 4; ++j) pk[j] = (_Float16)z[j];
                if (oke)
                    *(half4*)(w_out + (size_t)e*96 + nt*16 + lh*4) = pk;
            }
        }
        __builtin_amdgcn_sched_barrier(0);
    }
}

// ---------------- FUSED gather + epilogue, register/shuffle version ----------------
template<int ITER>
__global__ __launch_bounds__(256, 4)
void k_gather_epi(const int* __restrict__ rowptr, const int* __restrict__ eS,
                  const float4* __restrict__ pos4,
                  const float* __restrict__ h1, const _Float16* __restrict__ w_out,
                  float* AO, const int* __restrict__ elem,
                  const float* __restrict__ Wprod, const float* __restrict__ Wsc,
                  const float* __restrict__ Wp, const float* __restrict__ w_ro1,
                  const float* __restrict__ W_m1, const float* __restrict__ w_m2,
                  const float* __restrict__ Wlin_next, float* __restrict__ h1_next,
                  float* __restrict__ energy, int N)
{
    __shared__ float sWp[3 * 1024];
    __shared__ float sM1[(ITER == 1) ? 512 : 16];
    __shared__ float sm2[16];
    __shared__ float sro[32];
    __shared__ float sWl[(ITER == 0) ? 1024 : 16];

    for (int t = threadIdx.x; t < 3072; t += 256) sWp[t] = Wprod[t];
    if (ITER == 1)
        for (int t = threadIdx.x; t < 512; t += 256) sM1[t] = W_m1[t];
    if (ITER == 0)
        for (int t = threadIdx.x; t < 1024; t += 256) sWl[t] = Wlin_next[t];
    if (threadIdx.x < 16) sm2[threadIdx.x] = w_m2[threadIdx.x];
    if (threadIdx.x < 32) sro[threadIdx.x] = w_ro1[threadIdx.x];
    __syncthreads();

    int lane = threadIdx.x & 63;
    int gbase = lane & 56;                 // 8-lane group base (within wave)
    int g = threadIdx.x >> 3, j = threadIdx.x & 7, c0 = j * 4;
    int n = blockIdx.x * 32 + g;
    if (n >= N) return;                    // whole groups exit together; no barriers below

    // ---- register gather over this node's CSR range ----
    float acc[9][4];
    #pragma unroll
    for (int m = 0; m < 9; ++m)
        #pragma unroll
        for (int q = 0; q < 4; ++q) acc[m][q] = 0.f;
    float zacc = 0.f;

    float4 pn4 = pos4[n];
    float pnz = 0.f, pnz23 = 0.f;
    if (ITER == 0) { pnz = floorf(pn4.w * 0.25f); pnz23 = pn4.w - 4.0f * pnz; }

    int lo = rowptr[n], hi = rowptr[n+1];
    for (int k = lo; k < hi; ++k) {
        int s = eS[k];
        float4 ps4 = pos4[s];
        float dx = pn4.x - ps4.x;
        float dy = pn4.y - ps4.y;
        float dz = pn4.z - ps4.z;
        float r  = sqrtf(dx*dx + dy*dy + dz*dz + 1e-12f);
        float inv_r = 1.0f / r;
        float ux = dx*inv_r, uy = dy*inv_r, uz = dz*inv_r;
        const float s3 = 1.73205081f, s5 = 2.23606798f, s15 = 3.87298335f;
        float sh[9];
        sh[0] = 1.0f;
        sh[1] = s3 * ux; sh[2] = s3 * uy; sh[3] = s3 * uz;
        sh[4] = s15 * ux * uy; sh[5] = s15 * uy * uz;
        sh[6] = 0.5f * s5 * (3.0f * uz * uz - 1.0f);
        sh[7] = s15 * ux * uz;
        sh[8] = 0.5f * s15 * (ux * ux - uy * uy);

        if (ITER == 0) {
            float sz = floorf(ps4.w * 0.25f);
            float sz23 = ps4.w - 4.0f * sz;
            float u  = r * 0.2f;
            float u2 = u*u, u5 = u2*u2*u;
            float fcut = 1.0f - 21.0f*u5 + 35.0f*u5*u - 15.0f*u5*u2;
            float xx = r * (sz23 + pnz23) * 2.134471718f;
            float phi = 0.1818f*__expf(-3.2f*xx) + 0.5099f*__expf(-0.9423f*xx)
                      + 0.2802f*__expf(-0.4029f*xx) + 0.02817f*__expf(-0.2016f*xx);
            zacc += pnz * sz * inv_r * phi * fcut;
        }

        const _Float16* wp = w_out + (size_t)k * 96 + c0;
        half4 w0v = *(const half4*)(wp);
        half4 w1v = *(const half4*)(wp + 32);
        half4 w2v = *(const half4*)(wp + 64);
        float4 hv = *(const float4*)(h1 + (size_t)s * Cdim + c0);
        float hb[4] = {hv.x, hv.y, hv.z, hv.w};

        #pragma unroll
        for (int q = 0; q < 4; ++q) {
            float m0 = hb[q] * (float)w0v[q];
            float m1 = hb[q] * (float)w1v[q];
            float m2 = hb[q] * (float)w2v[q];
            acc[0][q] += m0;
            acc[1][q] += sh[1] * m1;
            acc[2][q] += sh[2] * m1;
            acc[3][q] += sh[3] * m1;
            acc[4][q] += sh[4] * m2;
            acc[5][q] += sh[5] * m2;
            acc[6][q] += sh[6] * m2;
            acc[7][q] += sh[7] * m2;
            acc[8][q] += sh[8] * m2;
        }
    }

    // ---- epilogue: all matmuls via shuffle-broadcast of the distributed vectors ----
    int el = elem[n];
    float4 hown = *(const float4*)(AO + (size_t)n * 576 + c0);   // current h
    float4 A0own = make_float4(acc[0][0]*0.0625f, acc[0][1]*0.0625f,
                               acc[0][2]*0.0625f, acc[0][3]*0.0625f);
    const float* Ws = Wsc + (size_t)el * 1024;
    float hs[4] = {0.f, 0.f, 0.f, 0.f};

    #pragma unroll
    for (int j2 = 0; j2 < 8; ++j2) {
        int src = gbase + j2;
        float4 a4 = shfl4(A0own, src);
        float4 h4 = shfl4(hown, src);
        float aq[4] = {a4.x, a4.y, a4.z, a4.w};
        float hq[4] = {h4.x, h4.y, h4.z, h4.w};
        #pragma unroll
        for (int q = 0; q < 4; ++q) {
            int c = j2 * 4 + q;
            float4 wp = *(const float4*)&sWp[c * 32 + c0];
            float4 wv = *(const float4*)(Ws + c * 32 + c0);
            hs[0] += aq[q] * wp.x + hq[q] * wv.x;
            hs[1] += aq[q] * wp.y + hq[q] * wv.y;
            hs[2] += aq[q] * wp.z + hq[q] * wv.z;
            hs[3] += aq[q] * wp.w + hq[q] * wv.w;
        }
    }
    // poly (register-local)
    {
        const float* wpb = Wp + el * 32;
        float4 p1 = *(const float4*)(wpb + c0);
        float4 p2 = *(const float4*)(wpb + 320 + c0);
        float4 p3 = *(const float4*)(wpb + 640 + c0);
        float p1a[4] = {p1.x, p1.y, p1.z, p1.w};
        float p2a[4] = {p2.x, p2.y, p2.z, p2.w};
        float p3a[4] = {p3.x, p3.y, p3.z, p3.w};
        #pragma unroll
        for (int d = 0; d < 4; ++d) {
            float A = acc[0][d] * 0.0625f, A2 = A * A;
            hs[d] += p1a[d] * A + p2a[d] * A2 + p3a[d] * (A2 * A);
        }
    }

    // energy readout
    float eadd;
    if (ITER == 0) {
        float a = hs[0]*sro[c0] + hs[1]*sro[c0+1] + hs[2]*sro[c0+2] + hs[3]*sro[c0+3];
        a += __shfl_xor(a, 1); a += __shfl_xor(a, 2); a += __shfl_xor(a, 4);
        eadd = a + 7.1998f * zacc;
    } else {
        float tj[16];
        #pragma unroll
        for (int q = 0; q < 16; ++q) {
            float tv = 0.f;
            #pragma unroll
            for (int d = 0; d < 4; ++d) tv += hs[d] * sM1[(c0 + d) * 16 + q];
            tv += __shfl_xor(tv, 1); tv += __shfl_xor(tv, 2); tv += __shfl_xor(tv, 4);
            tj[q] = tv;
        }
        float a = 0.f;
        #pragma unroll
        for (int q = 0; q < 16; ++q) a += silu_f(tj[q]) * sm2[q];
        eadd = a;
    }
    if (j == 0) energy[n] += eadd;

    const int outslot = (ITER == 0) ? 0 : 288;
    *(float4*)(AO + (size_t)n * 576 + outslot + c0) = make_float4(hs[0], hs[1], hs[2], hs[3]);

    // out[m] = (A[m]/16) @ Wprod[L[m]] for m=1..8
    #pragma unroll
    for (int m = 1; m <= 8; ++m) {
        const float* wb = sWp + ((m <= 3) ? 1 : 2) * 1024;
        float4 Am = make_float4(acc[m][0]*0.0625f, acc[m][1]*0.0625f,
                                acc[m][2]*0.0625f, acc[m][3]*0.0625f);
        float o[4] = {0.f, 0.f, 0.f, 0.f};
        #pragma unroll
        for (int j2 = 0; j2 < 8; ++j2) {
            float4 a4 = shfl4(Am, gbase + j2);
            float aq[4] = {a4.x, a4.y, a4.z, a4.w};
            #pragma unroll
            for (int q = 0; q < 4; ++q) {
                float4 wv = *(const float4*)&wb[(j2 * 4 + q) * 32 + c0];
                o[0] += aq[q] * wv.x; o[1] += aq[q] * wv.y;
                o[2] += aq[q] * wv.z; o[3] += aq[q] * wv.w;
            }
        }
        *(float4*)(AO + (size_t)n * 576 + outslot + m * 32 + c0) =
            make_float4(o[0], o[1], o[2], o[3]);
    }

    // ITER 0: h1 for iteration 1 = hs_full @ Wlin[1]
    if (ITER == 0) {
        float4 hsv = make_float4(hs[0], hs[1], hs[2], hs[3]);
        float o[4] = {0.f, 0.f, 0.f, 0.f};
        #pragma unroll
        for (int j2 = 0; j2 < 8; ++j2) {
            float4 h4 = shfl4(hsv, gbase + j2);
            float hq[4] = {h4.x, h4.y, h4.z, h4.w};
            #pragma unroll
            for (int q = 0; q < 4; ++q) {
                float4 wv = *(const float4*)&sWl[(j2 * 4 + q) * 32 + c0];
                o[0] += hq[q] * wv.x; o[1] += hq[q] * wv.y;
                o[2] += hq[q] * wv.z; o[3] += hq[q] * wv.w;
            }
        }
        *(float4*)(h1_next + (size_t)n * Cdim + c0) = make_float4(o[0], o[1], o[2], o[3]);
    }
}

extern "C" void kernel_launch(void* const* d_in, const int* in_sizes, int n_in,
                              void* d_out, int out_size, void* d_ws, size_t ws_size,
                              hipStream_t stream)
{
    const float* attrs   = (const float*)d_in[0];
    const float* pos     = (const float*)d_in[1];
    const int*   snd     = (const int*)d_in[2];
    const int*   rcv     = (const int*)d_in[3];
    const float* W_embed = (const float*)d_in[4];
    const float* atomE   = (const float*)d_in[5];
    const float* Wr0     = (const float*)d_in[6];
    const float* Wr1     = (const float*)d_in[7];
    const float* Wr2     = (const float*)d_in[8];
    const float* Wr3     = (const float*)d_in[9];
    const float* Wlin    = (const float*)d_in[10];
    const float* Wsc     = (const float*)d_in[11];
    const float* Wprod   = (const float*)d_in[12];
    const float* Wp      = (const float*)d_in[13];
    const float* w_ro1   = (const float*)d_in[14];
    const float* W_m1    = (const float*)d_in[15];
    const float* w_m2    = (const float*)d_in[16];

    const int N = in_sizes[1] / 3;
    const int E = in_sizes[2];

    float* energy = (float*)d_out;
    float* feats  = (float*)d_out + N;

    char* ws = (char*)d_ws;
    size_t off = 0;
    auto alloc = [&](size_t bytes) { void* p = ws + off; off = (off + bytes + 255) & ~(size_t)255; return p; };
    int*  deg    = (int*)alloc((size_t)N * 4);
    int*  cursor = (int*)alloc((size_t)N * 4);
    int*  rowptr = (int*)alloc((size_t)(N + 1) * 4);
    unsigned long long* mask = (unsigned long long*)alloc((size_t)((E + 63) / 64) * 8);
    int*  eS     = (int*)alloc((size_t)E * 4);
    int*  eT     = (int*)alloc((size_t)E * 4);
    int*  elem   = (int*)alloc((size_t)N * 4);
    float4* pos4 = (float4*)alloc((size_t)N * 16);
    float* h1a   = (float*)alloc((size_t)N * Cdim * 4);
    float* h1b   = (float*)alloc((size_t)N * Cdim * 4);
    _Float16* w_out = (_Float16*)(ws + off);

    k_node_init<<<(N + 255)/256, 256, 0, stream>>>(attrs, pos, W_embed, atomE, elem,
                                                   feats, energy, deg, pos4, N);
    k_filter<<<(E + 255)/256, 256, 0, stream>>>(pos4, snd, rcv, mask, deg, E);
    k_scan<<<1, 1024, 0, stream>>>(deg, rowptr, cursor, N);
    k_place<<<(E + 255)/256, 256, 0, stream>>>(snd, rcv, mask, cursor, eS, eT, E);
    k_h1<<<(N + 255)/256, 256, 0, stream>>>(feats, Wlin, h1a, N);

    const int NBLK = (N + 31) / 32;

    // ---- iteration 0 ----
    k_mlp<<<512, 256, 0, stream>>>(eS, eT, pos4,
        Wr0, Wr1, Wr2, Wr3, rowptr + N, w_out);
    k_gather_epi<0><<<NBLK, 256, 0, stream>>>(rowptr, eS, pos4, h1a, w_out,
        feats, elem, Wprod, Wsc, Wp, w_ro1, W_m1, w_m2,
        Wlin + 1024, h1b, energy, N);

    // ---- iteration 1 ----
    k_mlp<<<512, 256, 0, stream>>>(eS, eT, pos4,
        Wr0 + NBES * HDIM, Wr1 + HDIM * HDIM, Wr2 + HDIM * HDIM, Wr3 + HDIM * 96,
        rowptr + N, w_out);
    k_gather_epi<1><<<NBLK, 256, 0, stream>>>(rowptr, eS, pos4, h1b, w_out,
        feats, elem, Wprod + 3072, Wsc + 10240, Wp + 960, w_ro1, W_m1, w_m2,
        Wlin, h1b, energy, N);
}

// Round 9
// 293.849 us; speedup vs baseline: 1.7741x; 1.1624x over previous
//
#include <hip/hip_runtime.h>
#include <math.h>

static constexpr int Cdim = 32;   // C
static constexpr int NBES = 8;    // NB
static constexpr int HDIM = 64;   // H
static constexpr int ZDIM = 10;   // Z
static constexpr int TBLN = 4096; // radial table resolution

typedef _Float16 half8 __attribute__((ext_vector_type(8)));
typedef _Float16 half4 __attribute__((ext_vector_type(4)));
typedef float floatx4 __attribute__((ext_vector_type(4)));

__device__ __forceinline__ float silu_f(float x) {
    return x / (1.0f + __expf(-x));
}

__device__ __forceinline__ float4 shfl4(float4 v, int src) {
    return make_float4(__shfl(v.x, src), __shfl(v.y, src),
                       __shfl(v.z, src), __shfl(v.w, src));
}

// ---------------- EW = W_embed(10x32) @ Wlin0(32x32) ----------------
__global__ __launch_bounds__(320)
void k_wemb(const float* __restrict__ W_embed, const float* __restrict__ Wlin0,
            float* __restrict__ EW)
{
    int t = threadIdx.x;
    if (t >= ZDIM * Cdim) return;
    int z = t >> 5, d = t & 31;
    float acc = 0.f;
    #pragma unroll
    for (int c = 0; c < Cdim; ++c) acc += W_embed[z * Cdim + c] * Wlin0[c * Cdim + d];
    EW[t] = acc;
}

// ---------------- node init: elem, h, energy, deg=0, pos4, h1a=EW[elem] ----------------
__global__ __launch_bounds__(256)
void k_node_init(const float* __restrict__ attrs, const float* __restrict__ pos,
                 const float* __restrict__ W_embed, const float* __restrict__ atomE,
                 const float* __restrict__ EW, int* __restrict__ elem,
                 float* hOut /* feats base, stride 576 */, float* __restrict__ energy,
                 int* __restrict__ deg, float4* __restrict__ pos4,
                 float* __restrict__ h1a, int N)
{
    int n = blockIdx.x * blockDim.x + threadIdx.x;
    if (n >= N) return;
    int e = 0; float best = -1.0f;
    #pragma unroll
    for (int z = 0; z < ZDIM; ++z) {
        float v = attrs[n * ZDIM + z];
        if (v > best) { best = v; e = z; }
    }
    elem[n] = e;
    #pragma unroll
    for (int c = 0; c < Cdim; ++c) hOut[(size_t)n * 576 + c] = W_embed[e * Cdim + c];
    #pragma unroll
    for (int c4 = 0; c4 < 8; ++c4)
        *(float4*)(h1a + (size_t)n * Cdim + c4 * 4) = *(const float4*)(EW + e * Cdim + c4 * 4);
    energy[n] = atomE[e];
    deg[n] = 0;
    float zf = (float)(e + 1);
    pos4[n] = make_float4(pos[3*n+0], pos[3*n+1], pos[3*n+2],
                          4.0f * zf + powf(zf, 0.23f));
}

// ---------------- filter: d^2 < 25 -> ballot mask + degree count ----------------
__global__ __launch_bounds__(256)
void k_filter(const float4* __restrict__ pos4, const int* __restrict__ snd,
              const int* __restrict__ rcv, unsigned long long* __restrict__ mask,
              int* __restrict__ deg, int E)
{
    int e = blockIdx.x * blockDim.x + threadIdx.x;
    int ec = min(e, E - 1);
    int s = snd[ec], t = rcv[ec];
    float4 pt = pos4[t], ps = pos4[s];
    float dx = pt.x - ps.x, dy = pt.y - ps.y, dz = pt.z - ps.z;
    float d2 = dx*dx + dy*dy + dz*dz;
    bool pred = (e < E) && (d2 < 25.0f);
    unsigned long long m = __ballot(pred ? 1 : 0);
    if ((threadIdx.x & 63) == 0) mask[e >> 6] = m;
    if (pred) atomicAdd(&deg[t], 1);
}

// ---------------- single-block exclusive scan ----------------
__global__ __launch_bounds__(1024)
void k_scan(const int* __restrict__ deg, int* __restrict__ rowptr,
            int* __restrict__ cursor, int N)
{
    __shared__ int wsum[16];
    __shared__ int chunk_base;
    int tid = threadIdx.x;
    int lane = tid & 63, w = tid >> 6;
    if (tid == 0) chunk_base = 0;
    __syncthreads();
    for (int base = 0; base < N; base += 1024) {
        int i = base + tid;
        int v = (i < N) ? deg[i] : 0;
        int s = v;
        #pragma unroll
        for (int d = 1; d < 64; d <<= 1) {
            int u = __shfl_up(s, d);
            if (lane >= d) s += u;
        }
        if (lane == 63) wsum[w] = s;
        __syncthreads();
        if (w == 0 && lane < 16) {
            int x = wsum[lane];
            #pragma unroll
            for (int d = 1; d < 16; d <<= 1) {
                int u = __shfl_up(x, d);
                if (lane >= d) x += u;
            }
            wsum[lane] = x;
        }
        __syncthreads();
        int wave_off = (w == 0) ? 0 : wsum[w - 1];
        int excl = chunk_base + wave_off + (s - v);
        if (i < N) { rowptr[i] = excl; cursor[i] = excl; }
        int total = wsum[15];
        __syncthreads();
        if (tid == 0) chunk_base += total;
        __syncthreads();
    }
    if (tid == 0) rowptr[N] = chunk_base;
}

// ---------------- place: mask-gated CSR fill; precompute unit vec + r ----------------
__global__ __launch_bounds__(256)
void k_place(const int* __restrict__ snd, const int* __restrict__ rcv,
             const float4* __restrict__ pos4, const unsigned long long* __restrict__ mask,
             int* __restrict__ cursor, int* __restrict__ eS,
             float4* __restrict__ quad, int E)
{
    int e = blockIdx.x * blockDim.x + threadIdx.x;
    if (e >= E) return;
    if (!((mask[e >> 6] >> (e & 63)) & 1ull)) return;
    int t = rcv[e], s = snd[e];
    int slot = atomicAdd(&cursor[t], 1);
    eS[slot] = s;
    float4 pt = pos4[t], ps = pos4[s];
    float dx = pt.x - ps.x, dy = pt.y - ps.y, dz = pt.z - ps.z;
    float r  = sqrtf(dx*dx + dy*dy + dz*dz + 1e-12f);
    float inv_r = 1.0f / r;
    quad[slot] = make_float4(dx * inv_r, dy * inv_r, dz * inv_r, r);
}

// ---------------- radial table: F(r_q) for q=0..4095 via f16 MFMA MLP ----------------
__global__ __launch_bounds__(256, 2)
void k_table(const float* __restrict__ W0, const float* __restrict__ W1,
             const float* __restrict__ W2, const float* __restrict__ W3,
             float* __restrict__ table)
{
    __shared__ __align__(16) _Float16 sWt0[64*32];
    __shared__ __align__(16) _Float16 sWt1[64*64];
    __shared__ __align__(16) _Float16 sWt2[64*64];
    __shared__ __align__(16) _Float16 sWt3[96*64];
    __shared__ __align__(16) _Float16 sAct[4][64*64];

    for (int idx = threadIdx.x; idx < 64*32; idx += 256) {
        int n = idx >> 5, k = idx & 31;
        float v = (k < NBES) ? W0[k*64 + n] : 0.f;
        *(_Float16*)((char*)sWt0 + n*64 + ((k*2) ^ ((n&3)<<4))) = (_Float16)v;
    }
    for (int idx = threadIdx.x; idx < 64*64; idx += 256) {
        int k = idx >> 6, n = idx & 63;
        int byo = n*128 + ((k*2) ^ ((n&7)<<4));
        *(_Float16*)((char*)sWt1 + byo) = (_Float16)W1[idx];
        *(_Float16*)((char*)sWt2 + byo) = (_Float16)W2[idx];
    }
    for (int idx = threadIdx.x; idx < 64*96; idx += 256) {
        int k = idx / 96, n = idx - k*96;
        *(_Float16*)((char*)sWt3 + n*128 + ((k*2) ^ ((n&7)<<4))) = (_Float16)W3[idx];
    }
    __syncthreads();

    const int wid = threadIdx.x >> 6, lane = threadIdx.x & 63;
    const int l15 = lane & 15, lh = lane >> 4;
    char* actc = (char*)sAct[wid];

    half8 w1f[4], w2f[4][2], w3f[4][2], w4f[6][2];
    #pragma unroll
    for (int nt = 0; nt < 4; ++nt) {
        int nn = nt*16 + l15;
        w1f[nt] = *(half8*)((char*)sWt0 + nn*64 + ((lh*16) ^ ((nn&3)<<4)));
        #pragma unroll
        for (int ks = 0; ks < 2; ++ks) {
            w2f[nt][ks] = *(half8*)((char*)sWt1 + nn*128 + ((ks*64 + lh*16) ^ ((nn&7)<<4)));
            w3f[nt][ks] = *(half8*)((char*)sWt2 + nn*128 + ((ks*64 + lh*16) ^ ((nn&7)<<4)));
        }
    }
    #pragma unroll
    for (int nt = 0; nt < 6; ++nt) {
        int nn = nt*16 + l15;
        #pragma unroll
        for (int ks = 0; ks < 2; ++ks)
            w4f[nt][ks] = *(half8*)((char*)sWt3 + nn*128 + ((ks*64 + lh*16) ^ ((nn&7)<<4)));
    }

    int c0 = (blockIdx.x*4 + wid)*64;   // 16 blocks * 4 waves * 64 = 4096
    {
        int q = c0 + lane;
        float r = (q + 0.5f) * (5.0f / (float)TBLN);
        float inv_r = 1.0f / r;
        float u  = r * 0.2f;
        float u2 = u*u, u5 = u2*u2*u;
        float fcut = 1.0f - 21.0f*u5 + 35.0f*u5*u - 15.0f*u5*u2;
        float coef = 0.632455532f * inv_r * fcut;
        half8 rv;
        #pragma unroll
        for (int j = 0; j < NBES; ++j)
            rv[j] = (_Float16)(coef * __sinf((float)(j+1) * 0.628318531f * r));
        {
            int sw = (lane & 7) << 4;
            half8 zz = {};
            *(half8*)(actc + lane*128 + ( 0 ^ sw)) = rv;
            *(half8*)(actc + lane*128 + (16 ^ sw)) = zz;
            *(half8*)(actc + lane*128 + (32 ^ sw)) = zz;
            *(half8*)(actc + lane*128 + (48 ^ sw)) = zz;
        }
        __builtin_amdgcn_sched_barrier(0);

        // ---- L1 ----
        #pragma unroll
        for (int mt = 0; mt < 4; ++mt) {
            int rr = mt*16 + l15;
            int swz = (rr & 7) << 4;
            half8 act = *(half8*)(actc + rr*128 + ((lh*16) ^ swz));
            #pragma unroll
            for (int nt = 0; nt < 4; ++nt) {
                floatx4 z = {0.f,0.f,0.f,0.f};
                floatx4 d = __builtin_amdgcn_mfma_f32_16x16x32_f16(w1f[nt], act, z, 0,0,0);
                half4 pk;
                #pragma unroll
                for (int j = 0; j < 4; ++j) pk[j] = (_Float16)silu_f(d[j]);
                *(half4*)(actc + rr*128 + ((nt*32 + lh*8) ^ swz)) = pk;
            }
        }
        __builtin_amdgcn_sched_barrier(0);

        // ---- L2, L3 ----
        #pragma unroll
        for (int layer = 0; layer < 2; ++layer) {
            #pragma unroll
            for (int mt = 0; mt < 4; ++mt) {
                int rr = mt*16 + l15;
                int swz = (rr & 7) << 4;
                half8 a0 = *(half8*)(actc + rr*128 + ((      lh*16) ^ swz));
                half8 a1 = *(half8*)(actc + rr*128 + ((64 + lh*16) ^ swz));
                #pragma unroll
                for (int nt = 0; nt < 4; ++nt) {
                    floatx4 z = {0.f,0.f,0.f,0.f};
                    if (layer == 0) {
                        z = __builtin_amdgcn_mfma_f32_16x16x32_f16(w2f[nt][0], a0, z, 0,0,0);
                        z = __builtin_amdgcn_mfma_f32_16x16x32_f16(w2f[nt][1], a1, z, 0,0,0);
                    } else {
                        z = __builtin_amdgcn_mfma_f32_16x16x32_f16(w3f[nt][0], a0, z, 0,0,0);
                        z = __builtin_amdgcn_mfma_f32_16x16x32_f16(w3f[nt][1], a1, z, 0,0,0);
                    }
                    half4 pk;
                    #pragma unroll
                    for (int j = 0; j < 4; ++j) pk[j] = (_Float16)silu_f(z[j]);
                    *(half4*)(actc + rr*128 + ((nt*32 + lh*8) ^ swz)) = pk;
                }
            }
            __builtin_amdgcn_sched_barrier(0);
        }

        // ---- L4 -> f32 table stores ----
        #pragma unroll
        for (int mt = 0; mt < 4; ++mt) {
            int rr = mt*16 + l15;
            int swz = (rr & 7) << 4;
            half8 a0 = *(half8*)(actc + rr*128 + ((      lh*16) ^ swz));
            half8 a1 = *(half8*)(actc + rr*128 + ((64 + lh*16) ^ swz));
            int e = c0 + rr;
            #pragma unroll
            for (int nt = 0; nt < 6; ++nt) {
                floatx4 z = {0.f,0.f,0.f,0.f};
                z = __builtin_amdgcn_mfma_f32_16x16x32_f16(w4f[nt][0], a0, z, 0,0,0);
                z = __builtin_amdgcn_mfma_f32_16x16x32_f16(w4f[nt][1], a1, z, 0,0,0);
                *(floatx4*)(table + (size_t)e*96 + nt*16 + lh*4) = z;
            }
        }
    }
}

// ---------------- FUSED gather + epilogue, table-lerp version ----------------
template<int ITER>
__global__ __launch_bounds__(256, 4)
void k_gather_epi(const int* __restrict__ rowptr, const int* __restrict__ eS,
                  const float4* __restrict__ quad, const float4* __restrict__ pos4,
                  const float* __restrict__ h1, const float* __restrict__ table,
                  float* AO, const int* __restrict__ elem,
                  const float* __restrict__ Wprod, const float* __restrict__ Wsc,
                  const float* __restrict__ Wp, const float* __restrict__ w_ro1,
                  const float* __restrict__ W_m1, const float* __restrict__ w_m2,
                  const float* __restrict__ Wlin_next, float* __restrict__ h1_next,
                  float* __restrict__ energy, int N)
{
    __shared__ float sWp[3 * 1024];
    __shared__ float sM1[(ITER == 1) ? 512 : 16];
    __shared__ float sm2[16];
    __shared__ float sro[32];
    __shared__ float sWl[(ITER == 0) ? 1024 : 16];

    for (int t = threadIdx.x; t < 3072; t += 256) sWp[t] = Wprod[t];
    if (ITER == 1)
        for (int t = threadIdx.x; t < 512; t += 256) sM1[t] = W_m1[t];
    if (ITER == 0)
        for (int t = threadIdx.x; t < 1024; t += 256) sWl[t] = Wlin_next[t];
    if (threadIdx.x < 16) sm2[threadIdx.x] = w_m2[threadIdx.x];
    if (threadIdx.x < 32) sro[threadIdx.x] = w_ro1[threadIdx.x];
    __syncthreads();

    int lane = threadIdx.x & 63;
    int gbase = lane & 56;
    int g = threadIdx.x >> 3, j = threadIdx.x & 7, c0 = j * 4;
    int n = blockIdx.x * 32 + g;
    if (n >= N) return;

    float acc[9][4];
    #pragma unroll
    for (int m = 0; m < 9; ++m)
        #pragma unroll
        for (int q = 0; q < 4; ++q) acc[m][q] = 0.f;
    float zacc = 0.f;

    float pnz = 0.f, pnz23 = 0.f;
    if (ITER == 0) {
        float w = pos4[n].w;
        pnz = floorf(w * 0.25f); pnz23 = w - 4.0f * pnz;
    }

    int lo = rowptr[n], hi = rowptr[n+1];
    for (int k = lo; k < hi; ++k) {
        float4 qd = quad[k];
        float ux = qd.x, uy = qd.y, uz = qd.z, r = qd.w;
        const float s3 = 1.73205081f, s5 = 2.23606798f, s15 = 3.87298335f;
        float sh[9];
        sh[0] = 1.0f;
        sh[1] = s3 * ux; sh[2] = s3 * uy; sh[3] = s3 * uz;
        sh[4] = s15 * ux * uy; sh[5] = s15 * uy * uz;
        sh[6] = 0.5f * s5 * (3.0f * uz * uz - 1.0f);
        sh[7] = s15 * ux * uz;
        sh[8] = 0.5f * s15 * (ux * ux - uy * uy);

        // table lerp
        float x = r * ((float)TBLN / 5.0f) - 0.5f;
        x = fminf(fmaxf(x, 0.0f), (float)TBLN - 1.001f);
        int i0 = (int)x;
        float f = x - (float)i0;
        const float* T0 = table + (size_t)i0 * 96 + c0;
        const float* T1 = T0 + 96;
        float4 a0 = *(const float4*)(T0),      b0 = *(const float4*)(T1);
        float4 a1 = *(const float4*)(T0 + 32), b1 = *(const float4*)(T1 + 32);
        float4 a2 = *(const float4*)(T0 + 64), b2 = *(const float4*)(T1 + 64);

        int s = eS[k];
        float4 hv = *(const float4*)(h1 + (size_t)s * Cdim + c0);
        float hb[4] = {hv.x, hv.y, hv.z, hv.w};

        if (ITER == 0) {
            float wzs = ((const float*)(pos4 + s))[3];
            float sz = floorf(wzs * 0.25f);
            float sz23 = wzs - 4.0f * sz;
            float inv_r = 1.0f / r;
            float u  = r * 0.2f;
            float u2 = u*u, u5 = u2*u2*u;
            float fcut = 1.0f - 21.0f*u5 + 35.0f*u5*u - 15.0f*u5*u2;
            float xx = r * (sz23 + pnz23) * 2.134471718f;
            float phi = 0.1818f*__expf(-3.2f*xx) + 0.5099f*__expf(-0.9423f*xx)
                      + 0.2802f*__expf(-0.4029f*xx) + 0.02817f*__expf(-0.2016f*xx);
            zacc += pnz * sz * inv_r * phi * fcut;
        }

        float w0a[4] = {a0.x + f*(b0.x-a0.x), a0.y + f*(b0.y-a0.y),
                        a0.z + f*(b0.z-a0.z), a0.w + f*(b0.w-a0.w)};
        float w1a[4] = {a1.x + f*(b1.x-a1.x), a1.y + f*(b1.y-a1.y),
                        a1.z + f*(b1.z-a1.z), a1.w + f*(b1.w-a1.w)};
        float w2a[4] = {a2.x + f*(b2.x-a2.x), a2.y + f*(b2.y-a2.y),
                        a2.z + f*(b2.z-a2.z), a2.w + f*(b2.w-a2.w)};

        #pragma unroll
        for (int q = 0; q < 4; ++q) {
            float m0 = hb[q] * w0a[q];
            float m1 = hb[q] * w1a[q];
            float m2 = hb[q] * w2a[q];
            acc[0][q] += m0;
            acc[1][q] += sh[1] * m1;
            acc[2][q] += sh[2] * m1;
            acc[3][q] += sh[3] * m1;
            acc[4][q] += sh[4] * m2;
            acc[5][q] += sh[5] * m2;
            acc[6][q] += sh[6] * m2;
            acc[7][q] += sh[7] * m2;
            acc[8][q] += sh[8] * m2;
        }
    }

    // ---- epilogue (shuffle-broadcast matmuls) ----
    int el = elem[n];
    float4 hown = *(const float4*)(AO + (size_t)n * 576 + c0);
    float4 A0own = make_float4(acc[0][0]*0.0625f, acc[0][1]*0.0625f,
                               acc[0][2]*0.0625f, acc[0][3]*0.0625f);
    const float* Ws = Wsc + (size_t)el * 1024;
    float hs[4] = {0.f, 0.f, 0.f, 0.f};

    #pragma unroll
    for (int j2 = 0; j2 < 8; ++j2) {
        int src = gbase + j2;
        float4 a4 = shfl4(A0own, src);
        float4 h4 = shfl4(hown, src);
        float aq[4] = {a4.x, a4.y, a4.z, a4.w};
        float hq[4] = {h4.x, h4.y, h4.z, h4.w};
        #pragma unroll
        for (int q = 0; q < 4; ++q) {
            int c = j2 * 4 + q;
            float4 wp = *(const float4*)&sWp[c * 32 + c0];
            float4 wv = *(const float4*)(Ws + c * 32 + c0);
            hs[0] += aq[q] * wp.x + hq[q] * wv.x;
            hs[1] += aq[q] * wp.y + hq[q] * wv.y;
            hs[2] += aq[q] * wp.z + hq[q] * wv.z;
            hs[3] += aq[q] * wp.w + hq[q] * wv.w;
        }
    }
    {
        const float* wpb = Wp + el * 32;
        float4 p1 = *(const float4*)(wpb + c0);
        float4 p2 = *(const float4*)(wpb + 320 + c0);
        float4 p3 = *(const float4*)(wpb + 640 + c0);
        float p1a[4] = {p1.x, p1.y, p1.z, p1.w};
        float p2a[4] = {p2.x, p2.y, p2.z, p2.w};
        float p3a[4] = {p3.x, p3.y, p3.z, p3.w};
        #pragma unroll
        for (int d = 0; d < 4; ++d) {
            float A = acc[0][d] * 0.0625f, A2 = A * A;
            hs[d] += p1a[d] * A + p2a[d] * A2 + p3a[d] * (A2 * A);
        }
    }

    float eadd;
    if (ITER == 0) {
        float a = hs[0]*sro[c0] + hs[1]*sro[c0+1] + hs[2]*sro[c0+2] + hs[3]*sro[c0+3];
        a += __shfl_xor(a, 1); a += __shfl_xor(a, 2); a += __shfl_xor(a, 4);
        eadd = a + 7.1998f * zacc;
    } else {
        float tj[16];
        #pragma unroll
        for (int q = 0; q < 16; ++q) {
            float tv = 0.f;
            #pragma unroll
            for (int d = 0; d < 4; ++d) tv += hs[d] * sM1[(c0 + d) * 16 + q];
            tv += __shfl_xor(tv, 1); tv += __shfl_xor(tv, 2); tv += __shfl_xor(tv, 4);
            tj[q] = tv;
        }
        float a = 0.f;
        #pragma unroll
        for (int q = 0; q < 16; ++q) a += silu_f(tj[q]) * sm2[q];
        eadd = a;
    }
    if (j == 0) energy[n] += eadd;

    const int outslot = (ITER == 0) ? 0 : 288;
    *(float4*)(AO + (size_t)n * 576 + outslot + c0) = make_float4(hs[0], hs[1], hs[2], hs[3]);

    #pragma unroll
    for (int m = 1; m <= 8; ++m) {
        const float* wb = sWp + ((m <= 3) ? 1 : 2) * 1024;
        float4 Am = make_float4(acc[m][0]*0.0625f, acc[m][1]*0.0625f,
                                acc[m][2]*0.0625f, acc[m][3]*0.0625f);
        float o[4] = {0.f, 0.f, 0.f, 0.f};
        #pragma unroll
        for (int j2 = 0; j2 < 8; ++j2) {
            float4 a4 = shfl4(Am, gbase + j2);
            float aq[4] = {a4.x, a4.y, a4.z, a4.w};
            #pragma unroll
            for (int q = 0; q < 4; ++q) {
                float4 wv = *(const float4*)&wb[(j2 * 4 + q) * 32 + c0];
                o[0] += aq[q] * wv.x; o[1] += aq[q] * wv.y;
                o[2] += aq[q] * wv.z; o[3] += aq[q] * wv.w;
            }
        }
        *(float4*)(AO + (size_t)n * 576 + outslot + m * 32 + c0) =
            make_float4(o[0], o[1], o[2], o[3]);
    }

    if (ITER == 0) {
        float4 hsv = make_float4(hs[0], hs[1], hs[2], hs[3]);
        float o[4] = {0.f, 0.f, 0.f, 0.f};
        #pragma unroll
        for (int j2 = 0; j2 < 8; ++j2) {
            float4 h4 = shfl4(hsv, gbase + j2);
            float hq[4] = {h4.x, h4.y, h4.z, h4.w};
            #pragma unroll
            for (int q = 0; q < 4; ++q) {
                float4 wv = *(const float4*)&sWl[(j2 * 4 + q) * 32 + c0];
                o[0] += hq[q] * wv.x; o[1] += hq[q] * wv.y;
                o[2] += hq[q] * wv.z; o[3] += hq[q] * wv.w;
            }
        }
        *(float4*)(h1_next + (size_t)n * Cdim + c0) = make_float4(o[0], o[1], o[2], o[3]);
    }
}

extern "C" void kernel_launch(void* const* d_in, const int* in_sizes, int n_in,
                              void* d_out, int out_size, void* d_ws, size_t ws_size,
                              hipStream_t stream)
{
    const float* attrs   = (const float*)d_in[0];
    const float* pos     = (const float*)d_in[1];
    const int*   snd     = (const int*)d_in[2];
    const int*   rcv     = (const int*)d_in[3];
    const float* W_embed = (const float*)d_in[4];
    const float* atomE   = (const float*)d_in[5];
    const float* Wr0     = (const float*)d_in[6];
    const float* Wr1     = (const float*)d_in[7];
    const float* Wr2     = (const float*)d_in[8];
    const float* Wr3     = (const float*)d_in[9];
    const float* Wlin    = (const float*)d_in[10];
    const float* Wsc     = (const float*)d_in[11];
    const float* Wprod   = (const float*)d_in[12];
    const float* Wp      = (const float*)d_in[13];
    const float* w_ro1   = (const float*)d_in[14];
    const float* W_m1    = (const float*)d_in[15];
    const float* w_m2    = (const float*)d_in[16];

    const int N = in_sizes[1] / 3;
    const int E = in_sizes[2];

    float* energy = (float*)d_out;
    float* feats  = (float*)d_out + N;

    char* ws = (char*)d_ws;
    size_t off = 0;
    auto alloc = [&](size_t bytes) { void* p = ws + off; off = (off + bytes + 255) & ~(size_t)255; return p; };
    int*  deg    = (int*)alloc((size_t)N * 4);
    int*  cursor = (int*)alloc((size_t)N * 4);
    int*  rowptr = (int*)alloc((size_t)(N + 1) * 4);
    unsigned long long* mask = (unsigned long long*)alloc((size_t)((E + 63) / 64) * 8);
    int*  eS     = (int*)alloc((size_t)E * 4);
    float4* quad = (float4*)alloc((size_t)E * 16);
    int*  elem   = (int*)alloc((size_t)N * 4);
    float4* pos4 = (float4*)alloc((size_t)N * 16);
    float* h1a   = (float*)alloc((size_t)N * Cdim * 4);
    float* h1b   = (float*)alloc((size_t)N * Cdim * 4);
    float* EW    = (float*)alloc((size_t)ZDIM * Cdim * 4);
    float* table = (float*)alloc((size_t)TBLN * 96 * 4);

    k_wemb<<<1, 320, 0, stream>>>(W_embed, Wlin, EW);
    k_node_init<<<(N + 255)/256, 256, 0, stream>>>(attrs, pos, W_embed, atomE, EW, elem,
                                                   feats, energy, deg, pos4, h1a, N);
    k_filter<<<(E + 255)/256, 256, 0, stream>>>(pos4, snd, rcv, mask, deg, E);
    k_scan<<<1, 1024, 0, stream>>>(deg, rowptr, cursor, N);
    k_place<<<(E + 255)/256, 256, 0, stream>>>(snd, rcv, pos4, mask, cursor, eS, quad, E);

    const int NBLK = (N + 31) / 32;

    // ---- iteration 0 ----
    k_table<<<TBLN/256, 256, 0, stream>>>(Wr0, Wr1, Wr2, Wr3, table);
    k_gather_epi<0><<<NBLK, 256, 0, stream>>>(rowptr, eS, quad, pos4, h1a, table,
        feats, elem, Wprod, Wsc, Wp, w_ro1, W_m1, w_m2,
        Wlin + 1024, h1b, energy, N);

    // ---- iteration 1 ----
    k_table<<<TBLN/256, 256, 0, stream>>>(Wr0 + NBES * HDIM, Wr1 + HDIM * HDIM,
        Wr2 + HDIM * HDIM, Wr3 + HDIM * 96, table);
    k_gather_epi<1><<<NBLK, 256, 0, stream>>>(rowptr, eS, quad, pos4, h1b, table,
        feats, elem, Wprod + 3072, Wsc + 10240, Wp + 960, w_ro1, W_m1, w_m2,
        Wlin, h1b, energy, N);
}

// Round 10
// 244.393 us; speedup vs baseline: 2.1332x; 1.2024x over previous
//
#include <hip/hip_runtime.h>
#include <math.h>

static constexpr int Cdim = 32;   // C
static constexpr int NBES = 8;    // NB
static constexpr int HDIM = 64;   // H
static constexpr int ZDIM = 10;   // Z
static constexpr int TBLN = 4096; // radial table resolution

typedef _Float16 half8 __attribute__((ext_vector_type(8)));
typedef _Float16 half4 __attribute__((ext_vector_type(4)));
typedef float floatx4 __attribute__((ext_vector_type(4)));

__device__ __forceinline__ float silu_f(float x) {
    return x / (1.0f + __expf(-x));
}

__device__ __forceinline__ float4 shfl4(float4 v, int src) {
    return make_float4(__shfl(v.x, src), __shfl(v.y, src),
                       __shfl(v.z, src), __shfl(v.w, src));
}

// ---------------- EW = W_embed(10x32) @ Wlin0(32x32) ----------------
__global__ __launch_bounds__(320)
void k_wemb(const float* __restrict__ W_embed, const float* __restrict__ Wlin0,
            float* __restrict__ EW)
{
    int t = threadIdx.x;
    if (t >= ZDIM * Cdim) return;
    int z = t >> 5, d = t & 31;
    float acc = 0.f;
    #pragma unroll
    for (int c = 0; c < Cdim; ++c) acc += W_embed[z * Cdim + c] * Wlin0[c * Cdim + d];
    EW[t] = acc;
}

// ---------------- node init: elem, h, energy, deg=0, pos4, h1a=EW[elem] ----------------
__global__ __launch_bounds__(256)
void k_node_init(const float* __restrict__ attrs, const float* __restrict__ pos,
                 const float* __restrict__ W_embed, const float* __restrict__ atomE,
                 const float* __restrict__ EW, int* __restrict__ elem,
                 float* hOut /* feats base, stride 576 */, float* __restrict__ energy,
                 int* __restrict__ deg, float4* __restrict__ pos4,
                 float* __restrict__ h1a, int N)
{
    int n = blockIdx.x * blockDim.x + threadIdx.x;
    if (n >= N) return;
    int e = 0; float best = -1.0f;
    #pragma unroll
    for (int z = 0; z < ZDIM; ++z) {
        float v = attrs[n * ZDIM + z];
        if (v > best) { best = v; e = z; }
    }
    elem[n] = e;
    #pragma unroll
    for (int c = 0; c < Cdim; ++c) hOut[(size_t)n * 576 + c] = W_embed[e * Cdim + c];
    #pragma unroll
    for (int c4 = 0; c4 < 8; ++c4)
        *(float4*)(h1a + (size_t)n * Cdim + c4 * 4) = *(const float4*)(EW + e * Cdim + c4 * 4);
    energy[n] = atomE[e];
    deg[n] = 0;
    float zf = (float)(e + 1);
    pos4[n] = make_float4(pos[3*n+0], pos[3*n+1], pos[3*n+2],
                          4.0f * zf + powf(zf, 0.23f));
}

// ---------------- filter: d^2 < 25 -> ballot mask + degree count ----------------
__global__ __launch_bounds__(256)
void k_filter(const float4* __restrict__ pos4, const int* __restrict__ snd,
              const int* __restrict__ rcv, unsigned long long* __restrict__ mask,
              int* __restrict__ deg, int E)
{
    int e = blockIdx.x * blockDim.x + threadIdx.x;
    int ec = min(e, E - 1);
    int s = snd[ec], t = rcv[ec];
    float4 pt = pos4[t], ps = pos4[s];
    float dx = pt.x - ps.x, dy = pt.y - ps.y, dz = pt.z - ps.z;
    float d2 = dx*dx + dy*dy + dz*dz;
    bool pred = (e < E) && (d2 < 25.0f);
    unsigned long long m = __ballot(pred ? 1 : 0);
    if ((threadIdx.x & 63) == 0) mask[e >> 6] = m;
    if (pred) atomicAdd(&deg[t], 1);
}

// ---------------- single-block exclusive scan ----------------
__global__ __launch_bounds__(1024)
void k_scan(const int* __restrict__ deg, int* __restrict__ rowptr,
            int* __restrict__ cursor, int N)
{
    __shared__ int wsum[16];
    __shared__ int chunk_base;
    int tid = threadIdx.x;
    int lane = tid & 63, w = tid >> 6;
    if (tid == 0) chunk_base = 0;
    __syncthreads();
    for (int base = 0; base < N; base += 1024) {
        int i = base + tid;
        int v = (i < N) ? deg[i] : 0;
        int s = v;
        #pragma unroll
        for (int d = 1; d < 64; d <<= 1) {
            int u = __shfl_up(s, d);
            if (lane >= d) s += u;
        }
        if (lane == 63) wsum[w] = s;
        __syncthreads();
        if (w == 0 && lane < 16) {
            int x = wsum[lane];
            #pragma unroll
            for (int d = 1; d < 16; d <<= 1) {
                int u = __shfl_up(x, d);
                if (lane >= d) x += u;
            }
            wsum[lane] = x;
        }
        __syncthreads();
        int wave_off = (w == 0) ? 0 : wsum[w - 1];
        int excl = chunk_base + wave_off + (s - v);
        if (i < N) { rowptr[i] = excl; cursor[i] = excl; }
        int total = wsum[15];
        __syncthreads();
        if (tid == 0) chunk_base += total;
        __syncthreads();
    }
    if (tid == 0) rowptr[N] = chunk_base;
}

// ---------------- place: mask-gated CSR fill; precompute unit vec + r ----------------
__global__ __launch_bounds__(256)
void k_place(const int* __restrict__ snd, const int* __restrict__ rcv,
             const float4* __restrict__ pos4, const unsigned long long* __restrict__ mask,
             int* __restrict__ cursor, int* __restrict__ eS,
             float4* __restrict__ quad, int E)
{
    int e = blockIdx.x * blockDim.x + threadIdx.x;
    if (e >= E) return;
    if (!((mask[e >> 6] >> (e & 63)) & 1ull)) return;
    int t = rcv[e], s = snd[e];
    int slot = atomicAdd(&cursor[t], 1);
    eS[slot] = s;
    float4 pt = pos4[t], ps = pos4[s];
    float dx = pt.x - ps.x, dy = pt.y - ps.y, dz = pt.z - ps.z;
    float r  = sqrtf(dx*dx + dy*dy + dz*dz + 1e-12f);
    float inv_r = 1.0f / r;
    quad[slot] = make_float4(dx * inv_r, dy * inv_r, dz * inv_r, r);
}

// ---------------- radial table: F(r_q) for q=0..4095 via f16 MFMA MLP ----------------
__global__ __launch_bounds__(256, 2)
void k_table(const float* __restrict__ W0, const float* __restrict__ W1,
             const float* __restrict__ W2, const float* __restrict__ W3,
             float* __restrict__ table)
{
    __shared__ __align__(16) _Float16 sWt0[64*32];
    __shared__ __align__(16) _Float16 sWt1[64*64];
    __shared__ __align__(16) _Float16 sWt2[64*64];
    __shared__ __align__(16) _Float16 sWt3[96*64];
    __shared__ __align__(16) _Float16 sAct[4][64*64];

    for (int idx = threadIdx.x; idx < 64*32; idx += 256) {
        int n = idx >> 5, k = idx & 31;
        float v = (k < NBES) ? W0[k*64 + n] : 0.f;
        *(_Float16*)((char*)sWt0 + n*64 + ((k*2) ^ ((n&3)<<4))) = (_Float16)v;
    }
    for (int idx = threadIdx.x; idx < 64*64; idx += 256) {
        int k = idx >> 6, n = idx & 63;
        int byo = n*128 + ((k*2) ^ ((n&7)<<4));
        *(_Float16*)((char*)sWt1 + byo) = (_Float16)W1[idx];
        *(_Float16*)((char*)sWt2 + byo) = (_Float16)W2[idx];
    }
    for (int idx = threadIdx.x; idx < 64*96; idx += 256) {
        int k = idx / 96, n = idx - k*96;
        *(_Float16*)((char*)sWt3 + n*128 + ((k*2) ^ ((n&7)<<4))) = (_Float16)W3[idx];
    }
    __syncthreads();

    const int wid = threadIdx.x >> 6, lane = threadIdx.x & 63;
    const int l15 = lane & 15, lh = lane >> 4;
    char* actc = (char*)sAct[wid];

    half8 w1f[4], w2f[4][2], w3f[4][2], w4f[6][2];
    #pragma unroll
    for (int nt = 0; nt < 4; ++nt) {
        int nn = nt*16 + l15;
        w1f[nt] = *(half8*)((char*)sWt0 + nn*64 + ((lh*16) ^ ((nn&3)<<4)));
        #pragma unroll
        for (int ks = 0; ks < 2; ++ks) {
            w2f[nt][ks] = *(half8*)((char*)sWt1 + nn*128 + ((ks*64 + lh*16) ^ ((nn&7)<<4)));
            w3f[nt][ks] = *(half8*)((char*)sWt2 + nn*128 + ((ks*64 + lh*16) ^ ((nn&7)<<4)));
        }
    }
    #pragma unroll
    for (int nt = 0; nt < 6; ++nt) {
        int nn = nt*16 + l15;
        #pragma unroll
        for (int ks = 0; ks < 2; ++ks)
            w4f[nt][ks] = *(half8*)((char*)sWt3 + nn*128 + ((ks*64 + lh*16) ^ ((nn&7)<<4)));
    }

    int c0 = (blockIdx.x*4 + wid)*64;
    {
        int q = c0 + lane;
        float r = (q + 0.5f) * (5.0f / (float)TBLN);
        float inv_r = 1.0f / r;
        float u  = r * 0.2f;
        float u2 = u*u, u5 = u2*u2*u;
        float fcut = 1.0f - 21.0f*u5 + 35.0f*u5*u - 15.0f*u5*u2;
        float coef = 0.632455532f * inv_r * fcut;
        half8 rv;
        #pragma unroll
        for (int j = 0; j < NBES; ++j)
            rv[j] = (_Float16)(coef * __sinf((float)(j+1) * 0.628318531f * r));
        {
            int sw = (lane & 7) << 4;
            half8 zz = {};
            *(half8*)(actc + lane*128 + ( 0 ^ sw)) = rv;
            *(half8*)(actc + lane*128 + (16 ^ sw)) = zz;
            *(half8*)(actc + lane*128 + (32 ^ sw)) = zz;
            *(half8*)(actc + lane*128 + (48 ^ sw)) = zz;
        }
        __builtin_amdgcn_sched_barrier(0);

        // ---- L1 ----
        #pragma unroll
        for (int mt = 0; mt < 4; ++mt) {
            int rr = mt*16 + l15;
            int swz = (rr & 7) << 4;
            half8 act = *(half8*)(actc + rr*128 + ((lh*16) ^ swz));
            #pragma unroll
            for (int nt = 0; nt < 4; ++nt) {
                floatx4 z = {0.f,0.f,0.f,0.f};
                floatx4 d = __builtin_amdgcn_mfma_f32_16x16x32_f16(w1f[nt], act, z, 0,0,0);
                half4 pk;
                #pragma unroll
                for (int j = 0; j < 4; ++j) pk[j] = (_Float16)silu_f(d[j]);
                *(half4*)(actc + rr*128 + ((nt*32 + lh*8) ^ swz)) = pk;
            }
        }
        __builtin_amdgcn_sched_barrier(0);

        // ---- L2, L3 ----
        #pragma unroll
        for (int layer = 0; layer < 2; ++layer) {
            #pragma unroll
            for (int mt = 0; mt < 4; ++mt) {
                int rr = mt*16 + l15;
                int swz = (rr & 7) << 4;
                half8 a0 = *(half8*)(actc + rr*128 + ((      lh*16) ^ swz));
                half8 a1 = *(half8*)(actc + rr*128 + ((64 + lh*16) ^ swz));
                #pragma unroll
                for (int nt = 0; nt < 4; ++nt) {
                    floatx4 z = {0.f,0.f,0.f,0.f};
                    if (layer == 0) {
                        z = __builtin_amdgcn_mfma_f32_16x16x32_f16(w2f[nt][0], a0, z, 0,0,0);
                        z = __builtin_amdgcn_mfma_f32_16x16x32_f16(w2f[nt][1], a1, z, 0,0,0);
                    } else {
                        z = __builtin_amdgcn_mfma_f32_16x16x32_f16(w3f[nt][0], a0, z, 0,0,0);
                        z = __builtin_amdgcn_mfma_f32_16x16x32_f16(w3f[nt][1], a1, z, 0,0,0);
                    }
                    half4 pk;
                    #pragma unroll
                    for (int j = 0; j < 4; ++j) pk[j] = (_Float16)silu_f(z[j]);
                    *(half4*)(actc + rr*128 + ((nt*32 + lh*8) ^ swz)) = pk;
                }
            }
            __builtin_amdgcn_sched_barrier(0);
        }

        // ---- L4 -> f32 table stores ----
        #pragma unroll
        for (int mt = 0; mt < 4; ++mt) {
            int rr = mt*16 + l15;
            int swz = (rr & 7) << 4;
            half8 a0 = *(half8*)(actc + rr*128 + ((      lh*16) ^ swz));
            half8 a1 = *(half8*)(actc + rr*128 + ((64 + lh*16) ^ swz));
            int e = c0 + rr;
            #pragma unroll
            for (int nt = 0; nt < 6; ++nt) {
                floatx4 z = {0.f,0.f,0.f,0.f};
                z = __builtin_amdgcn_mfma_f32_16x16x32_f16(w4f[nt][0], a0, z, 0,0,0);
                z = __builtin_amdgcn_mfma_f32_16x16x32_f16(w4f[nt][1], a1, z, 0,0,0);
                *(floatx4*)(table + (size_t)e*96 + nt*16 + lh*4) = z;
            }
        }
    }
}

// ---------------- FUSED gather + MFMA epilogue ----------------
template<int ITER>
__global__ __launch_bounds__(256, 4)
void k_gather_epi(const int* __restrict__ rowptr, const int* __restrict__ eS,
                  const float4* __restrict__ quad, const float4* __restrict__ pos4,
                  const float* __restrict__ h1, const float* __restrict__ table,
                  float* AO, const int* __restrict__ elem,
                  const float* __restrict__ Wprod, const float* __restrict__ Wsc,
                  const float* __restrict__ Wp, const float* __restrict__ w_ro1,
                  const float* __restrict__ W_m1, const float* __restrict__ w_m2,
                  const float* __restrict__ Wlin_next, float* __restrict__ h1_next,
                  float* __restrict__ energy, int N)
{
    __shared__ float sWp[1024];                     // Wprod[0] (m=0 / hs path)
    __shared__ __align__(16) _Float16 sWt16[2048];  // Wprod[1],[2] transposed f16
    __shared__ float sM1[(ITER == 1) ? 512 : 16];
    __shared__ float sm2[16];
    __shared__ float sro[32];
    __shared__ float sWl[(ITER == 0) ? 1024 : 16];
    __shared__ __align__(16) _Float16 sA16[32 * 296];  // [32 nodes][pad 592B] A_m f16

    for (int t = threadIdx.x; t < 1024; t += 256) sWp[t] = Wprod[t];
    for (int t = threadIdx.x; t < 2048; t += 256) {
        int l = t >> 10, rem = t & 1023, d = rem >> 5, c = rem & 31;
        *(_Float16*)((char*)sWt16 + l*2048 + d*64 + ((c*2) ^ ((d&3)<<4))) =
            (_Float16)Wprod[(l + 1) * 1024 + c * 32 + d];
    }
    if (ITER == 1)
        for (int t = threadIdx.x; t < 512; t += 256) sM1[t] = W_m1[t];
    if (ITER == 0)
        for (int t = threadIdx.x; t < 1024; t += 256) sWl[t] = Wlin_next[t];
    if (threadIdx.x < 16) sm2[threadIdx.x] = w_m2[threadIdx.x];
    if (threadIdx.x < 32) sro[threadIdx.x] = w_ro1[threadIdx.x];

    int lane = threadIdx.x & 63;
    int gbase = lane & 56;
    int g = threadIdx.x >> 3, j = threadIdx.x & 7, c0 = j * 4;
    int n = blockIdx.x * 32 + g;
    bool valid = (n < N);

    float acc[9][4];
    #pragma unroll
    for (int m = 0; m < 9; ++m)
        #pragma unroll
        for (int q = 0; q < 4; ++q) acc[m][q] = 0.f;
    float zacc = 0.f;

    if (valid) {
        float pnz = 0.f, pnz23 = 0.f;
        if (ITER == 0) {
            float w = pos4[n].w;
            pnz = floorf(w * 0.25f); pnz23 = w - 4.0f * pnz;
        }
        int lo = rowptr[n], hi = rowptr[n+1];
        for (int k = lo; k < hi; ++k) {
            float4 qd = quad[k];
            float ux = qd.x, uy = qd.y, uz = qd.z, r = qd.w;
            const float s3 = 1.73205081f, s5 = 2.23606798f, s15 = 3.87298335f;
            float sh[9];
            sh[0] = 1.0f;
            sh[1] = s3 * ux; sh[2] = s3 * uy; sh[3] = s3 * uz;
            sh[4] = s15 * ux * uy; sh[5] = s15 * uy * uz;
            sh[6] = 0.5f * s5 * (3.0f * uz * uz - 1.0f);
            sh[7] = s15 * ux * uz;
            sh[8] = 0.5f * s15 * (ux * ux - uy * uy);

            float x = r * ((float)TBLN / 5.0f) - 0.5f;
            x = fminf(fmaxf(x, 0.0f), (float)TBLN - 1.001f);
            int i0 = (int)x;
            float f = x - (float)i0;
            const float* T0 = table + (size_t)i0 * 96 + c0;
            const float* T1 = T0 + 96;
            float4 a0 = *(const float4*)(T0),      b0 = *(const float4*)(T1);
            float4 a1 = *(const float4*)(T0 + 32), b1 = *(const float4*)(T1 + 32);
            float4 a2 = *(const float4*)(T0 + 64), b2 = *(const float4*)(T1 + 64);

            int s = eS[k];
            float4 hv = *(const float4*)(h1 + (size_t)s * Cdim + c0);
            float hb[4] = {hv.x, hv.y, hv.z, hv.w};

            if (ITER == 0) {
                float wzs = ((const float*)(pos4 + s))[3];
                float sz = floorf(wzs * 0.25f);
                float sz23 = wzs - 4.0f * sz;
                float inv_r = 1.0f / r;
                float u  = r * 0.2f;
                float u2 = u*u, u5 = u2*u2*u;
                float fcut = 1.0f - 21.0f*u5 + 35.0f*u5*u - 15.0f*u5*u2;
                float xx = r * (sz23 + pnz23) * 2.134471718f;
                float phi = 0.1818f*__expf(-3.2f*xx) + 0.5099f*__expf(-0.9423f*xx)
                          + 0.2802f*__expf(-0.4029f*xx) + 0.02817f*__expf(-0.2016f*xx);
                zacc += pnz * sz * inv_r * phi * fcut;
            }

            float w0a[4] = {a0.x + f*(b0.x-a0.x), a0.y + f*(b0.y-a0.y),
                            a0.z + f*(b0.z-a0.z), a0.w + f*(b0.w-a0.w)};
            float w1a[4] = {a1.x + f*(b1.x-a1.x), a1.y + f*(b1.y-a1.y),
                            a1.z + f*(b1.z-a1.z), a1.w + f*(b1.w-a1.w)};
            float w2a[4] = {a2.x + f*(b2.x-a2.x), a2.y + f*(b2.y-a2.y),
                            a2.z + f*(b2.z-a2.z), a2.w + f*(b2.w-a2.w)};

            #pragma unroll
            for (int q = 0; q < 4; ++q) {
                float m0 = hb[q] * w0a[q];
                float m1 = hb[q] * w1a[q];
                float m2 = hb[q] * w2a[q];
                acc[0][q] += m0;
                acc[1][q] += sh[1] * m1;
                acc[2][q] += sh[2] * m1;
                acc[3][q] += sh[3] * m1;
                acc[4][q] += sh[4] * m2;
                acc[5][q] += sh[5] * m2;
                acc[6][q] += sh[6] * m2;
                acc[7][q] += sh[7] * m2;
                acc[8][q] += sh[8] * m2;
            }
        }
        // stage A_m (m=1..8, scaled /16) to LDS f16 for MFMA phase
        #pragma unroll
        for (int m = 1; m <= 8; ++m) {
            half4 pk;
            #pragma unroll
            for (int q = 0; q < 4; ++q) pk[q] = (_Float16)(acc[m][q] * 0.0625f);
            *(half4*)((char*)sA16 + g * 592 + m * 64 + j * 8) = pk;
        }
    }
    __syncthreads();   // covers weight staging + sA16

    // ---- MFMA phase: out[m] = (A_m/16) @ Wprod[L[m]], m=1..8 ----
    {
        int w = threadIdx.x >> 6;
        int l15 = lane & 15, lh = lane >> 4;
        int nhalf = (w >> 1) * 16;
        int mbase = (w & 1) * 4 + 1;
        int node = blockIdx.x * 32 + nhalf + l15;
        const int outslot = (ITER == 0) ? 0 : 288;

        half8 af[2][2];
        #pragma unroll
        for (int l = 0; l < 2; ++l)
            #pragma unroll
            for (int nt = 0; nt < 2; ++nt) {
                int row = nt * 16 + l15;
                af[l][nt] = *(half8*)((char*)sWt16 + l*2048 + row*64 +
                                      ((lh*16) ^ ((row&3)<<4)));
            }
        #pragma unroll
        for (int mi = 0; mi < 4; ++mi) {
            int m = mbase + mi;
            int l = (m <= 3) ? 0 : 1;
            half8 bf = *(half8*)((char*)sA16 + (nhalf + l15) * 592 + m * 64 + lh * 16);
            #pragma unroll
            for (int nt = 0; nt < 2; ++nt) {
                floatx4 z = {0.f, 0.f, 0.f, 0.f};
                z = __builtin_amdgcn_mfma_f32_16x16x32_f16(af[l][nt], bf, z, 0, 0, 0);
                if (node < N)
                    *(floatx4*)(AO + (size_t)node * 576 + outslot + m * 32 +
                                nt * 16 + lh * 4) = z;
            }
        }
    }

    // ---- hs / scalar channel (shuffle form) ----
    if (valid) {
        int el = elem[n];
        float4 hown = *(const float4*)(AO + (size_t)n * 576 + c0);
        float4 A0own = make_float4(acc[0][0]*0.0625f, acc[0][1]*0.0625f,
                                   acc[0][2]*0.0625f, acc[0][3]*0.0625f);
        const float* Ws = Wsc + (size_t)el * 1024;
        float hs[4] = {0.f, 0.f, 0.f, 0.f};

        #pragma unroll
        for (int j2 = 0; j2 < 8; ++j2) {
            int src = gbase + j2;
            float4 a4 = shfl4(A0own, src);
            float4 h4 = shfl4(hown, src);
            float aq[4] = {a4.x, a4.y, a4.z, a4.w};
            float hq[4] = {h4.x, h4.y, h4.z, h4.w};
            #pragma unroll
            for (int q = 0; q < 4; ++q) {
                int c = j2 * 4 + q;
                float4 wp = *(const float4*)&sWp[c * 32 + c0];
                float4 wv = *(const float4*)(Ws + c * 32 + c0);
                hs[0] += aq[q] * wp.x + hq[q] * wv.x;
                hs[1] += aq[q] * wp.y + hq[q] * wv.y;
                hs[2] += aq[q] * wp.z + hq[q] * wv.z;
                hs[3] += aq[q] * wp.w + hq[q] * wv.w;
            }
        }
        {
            const float* wpb = Wp + el * 32;
            float4 p1 = *(const float4*)(wpb + c0);
            float4 p2 = *(const float4*)(wpb + 320 + c0);
            float4 p3 = *(const float4*)(wpb + 640 + c0);
            float p1a[4] = {p1.x, p1.y, p1.z, p1.w};
            float p2a[4] = {p2.x, p2.y, p2.z, p2.w};
            float p3a[4] = {p3.x, p3.y, p3.z, p3.w};
            #pragma unroll
            for (int d = 0; d < 4; ++d) {
                float A = acc[0][d] * 0.0625f, A2 = A * A;
                hs[d] += p1a[d] * A + p2a[d] * A2 + p3a[d] * (A2 * A);
            }
        }

        float eadd;
        if (ITER == 0) {
            float a = hs[0]*sro[c0] + hs[1]*sro[c0+1] + hs[2]*sro[c0+2] + hs[3]*sro[c0+3];
            a += __shfl_xor(a, 1); a += __shfl_xor(a, 2); a += __shfl_xor(a, 4);
            eadd = a + 7.1998f * zacc;
        } else {
            float tj[16];
            #pragma unroll
            for (int q = 0; q < 16; ++q) {
                float tv = 0.f;
                #pragma unroll
                for (int d = 0; d < 4; ++d) tv += hs[d] * sM1[(c0 + d) * 16 + q];
                tv += __shfl_xor(tv, 1); tv += __shfl_xor(tv, 2); tv += __shfl_xor(tv, 4);
                tj[q] = tv;
            }
            float a = 0.f;
            #pragma unroll
            for (int q = 0; q < 16; ++q) a += silu_f(tj[q]) * sm2[q];
            eadd = a;
        }
        if (j == 0) energy[n] += eadd;

        const int outslot = (ITER == 0) ? 0 : 288;
        *(float4*)(AO + (size_t)n * 576 + outslot + c0) = make_float4(hs[0], hs[1], hs[2], hs[3]);

        if (ITER == 0) {
            float4 hsv = make_float4(hs[0], hs[1], hs[2], hs[3]);
            float o[4] = {0.f, 0.f, 0.f, 0.f};
            #pragma unroll
            for (int j2 = 0; j2 < 8; ++j2) {
                float4 h4 = shfl4(hsv, gbase + j2);
                float hq[4] = {h4.x, h4.y, h4.z, h4.w};
                #pragma unroll
                for (int q = 0; q < 4; ++q) {
                    float4 wv = *(const float4*)&sWl[(j2 * 4 + q) * 32 + c0];
                    o[0] += hq[q] * wv.x; o[1] += hq[q] * wv.y;
                    o[2] += hq[q] * wv.z; o[3] += hq[q] * wv.w;
                }
            }
            *(float4*)(h1_next + (size_t)n * Cdim + c0) = make_float4(o[0], o[1], o[2], o[3]);
        }
    }
}

extern "C" void kernel_launch(void* const* d_in, const int* in_sizes, int n_in,
                              void* d_out, int out_size, void* d_ws, size_t ws_size,
                              hipStream_t stream)
{
    const float* attrs   = (const float*)d_in[0];
    const float* pos     = (const float*)d_in[1];
    const int*   snd     = (const int*)d_in[2];
    const int*   rcv     = (const int*)d_in[3];
    const float* W_embed = (const float*)d_in[4];
    const float* atomE   = (const float*)d_in[5];
    const float* Wr0     = (const float*)d_in[6];
    const float* Wr1     = (const float*)d_in[7];
    const float* Wr2     = (const float*)d_in[8];
    const float* Wr3     = (const float*)d_in[9];
    const float* Wlin    = (const float*)d_in[10];
    const float* Wsc     = (const float*)d_in[11];
    const float* Wprod   = (const float*)d_in[12];
    const float* Wp      = (const float*)d_in[13];
    const float* w_ro1   = (const float*)d_in[14];
    const float* W_m1    = (const float*)d_in[15];
    const float* w_m2    = (const float*)d_in[16];

    const int N = in_sizes[1] / 3;
    const int E = in_sizes[2];

    float* energy = (float*)d_out;
    float* feats  = (float*)d_out + N;

    char* ws = (char*)d_ws;
    size_t off = 0;
    auto alloc = [&](size_t bytes) { void* p = ws + off; off = (off + bytes + 255) & ~(size_t)255; return p; };
    int*  deg    = (int*)alloc((size_t)N * 4);
    int*  cursor = (int*)alloc((size_t)N * 4);
    int*  rowptr = (int*)alloc((size_t)(N + 1) * 4);
    unsigned long long* mask = (unsigned long long*)alloc((size_t)((E + 63) / 64) * 8);
    int*  eS     = (int*)alloc((size_t)E * 4);
    float4* quad = (float4*)alloc((size_t)E * 16);
    int*  elem   = (int*)alloc((size_t)N * 4);
    float4* pos4 = (float4*)alloc((size_t)N * 16);
    float* h1a   = (float*)alloc((size_t)N * Cdim * 4);
    float* h1b   = (float*)alloc((size_t)N * Cdim * 4);
    float* EW    = (float*)alloc((size_t)ZDIM * Cdim * 4);
    float* table = (float*)alloc((size_t)TBLN * 96 * 4);

    k_wemb<<<1, 320, 0, stream>>>(W_embed, Wlin, EW);
    k_node_init<<<(N + 255)/256, 256, 0, stream>>>(attrs, pos, W_embed, atomE, EW, elem,
                                                   feats, energy, deg, pos4, h1a, N);
    k_filter<<<(E + 255)/256, 256, 0, stream>>>(pos4, snd, rcv, mask, deg, E);
    k_scan<<<1, 1024, 0, stream>>>(deg, rowptr, cursor, N);
    k_place<<<(E + 255)/256, 256, 0, stream>>>(snd, rcv, pos4, mask, cursor, eS, quad, E);

    const int NBLK = (N + 31) / 32;

    // ---- iteration 0 ----
    k_table<<<TBLN/256, 256, 0, stream>>>(Wr0, Wr1, Wr2, Wr3, table);
    k_gather_epi<0><<<NBLK, 256, 0, stream>>>(rowptr, eS, quad, pos4, h1a, table,
        feats, elem, Wprod, Wsc, Wp, w_ro1, W_m1, w_m2,
        Wlin + 1024, h1b, energy, N);

    // ---- iteration 1 ----
    k_table<<<TBLN/256, 256, 0, stream>>>(Wr0 + NBES * HDIM, Wr1 + HDIM * HDIM,
        Wr2 + HDIM * HDIM, Wr3 + HDIM * 96, table);
    k_gather_epi<1><<<NBLK, 256, 0, stream>>>(rowptr, eS, quad, pos4, h1b, table,
        feats, elem, Wprod + 3072, Wsc + 10240, Wp + 960, w_ro1, W_m1, w_m2,
        Wlin, h1b, energy, N);
}